// Round 3
// baseline (801.941 us; speedup 1.0000x reference)
//
#include <hip/hip_runtime.h>
#include <math.h>

#define BT_TOK 32768
#define D_IN   1024
#define H1D    768
#define H2D    512
#define KCB    512

typedef _Float16 f16;
typedef _Float16 half8v __attribute__((ext_vector_type(8)));
typedef float f32x4 __attribute__((ext_vector_type(4)));

#define GLDS16(g, l) \
    __builtin_amdgcn_global_load_lds((const __attribute__((address_space(1))) void*)(g), \
                                     (__attribute__((address_space(3))) void*)(l), 16, 0, 0)

// split convention: hi = f16(v), lo = f16((v-hi)*2048); v ~= hi + lo/2048
__device__ __forceinline__ void splitf(float v, f16& h, f16& l) {
    h = (f16)v;
    l = (f16)((v - (float)h) * 2048.f);
}

// ---------------------------------------------------------------------------
// Split-FP16 MFMA GEMM, depth-3 software pipeline (T3+T4+T5):
//   BM=256 x BN=128, BK=32, 512 threads = 8 waves (4M x 2N), per-wave 64x64.
//   LDS: TRIPLE-buffered {Ah,Al,Bh,Bl} = 144 KiB, 1 block/CU.
//   Iter t: issue STAGE(tile t+2) -> s_waitcnt vmcnt(12) (tiles t+1,t+2 stay
//   in flight; NEVER drains to 0 in the main loop - T4) -> barrier -> two
//   MFMA phases (lgkmcnt(0)+sched_barrier+setprio around each cluster).
//   Buffer for tile t+2 was last read in iter t-1; end-of-iter barrier makes
//   the overwrite safe. ~2 tiles of MFMA cover (~1000 cyc) > HBM latency.
//   Chunk slot XOR-swizzled with (row>>1)&3 on BOTH the staging source and
//   the fragment read (0-conflict, verified round 1). XCD-chunked block
//   swizzle when nwg % 8 == 0.
// EPI 0: +bias -> f16 pair. 1: VQ tile-argmin. 2: +bias,relu -> f16 pair.
// EPI 3: +bias -> fp32.
// ---------------------------------------------------------------------------
template<int EPI>
__global__ __launch_bounds__(512, 2) void sgemm_k(
    const f16* __restrict__ Ah, const f16* __restrict__ Al,
    const f16* __restrict__ Bh, const f16* __restrict__ Bl,
    const float* __restrict__ bias,
    f16* __restrict__ Ch, f16* __restrict__ Cl,
    float* __restrict__ Cf,
    const float* __restrict__ cnorm,
    float* __restrict__ cand_v, int* __restrict__ cand_i,
    int N, int Kd)
{
    // [0,48K): sAh 3 bufs x 16K    [48K,96K): sAl 3 x 16K
    // [96K,120K): sBh 3 x 8K       [120K,144K): sBl 3 x 8K
    __shared__ __align__(16) char lds[147456];
    char* const ldsb = lds;

    const int t = threadIdx.x;
    const int lane = t & 63, wave = t >> 6;
    const int wm = wave & 3, wn = wave >> 2;

    const int nwg = gridDim.x * gridDim.y;
    int flat = blockIdx.y * gridDim.x + blockIdx.x;
    if ((nwg & 7) == 0) flat = (flat & 7) * (nwg >> 3) + (flat >> 3);
    const int bx = flat % gridDim.x;
    const int by = flat / gridDim.x;
    const int row0 = by * 256, col0 = bx * 128;

    f32x4 acc_h[4][4], acc_l[4][4];
#pragma unroll
    for (int i = 0; i < 4; ++i)
#pragma unroll
        for (int j = 0; j < 4; ++j) {
            acc_h[i][j] = (f32x4){0.f, 0.f, 0.f, 0.f};
            acc_l[i][j] = (f32x4){0.f, 0.f, 0.f, 0.f};
        }

    // Staging: 512 threads cover 128 rows x 4 chunks of 16 B per GLDS round.
    // row = t>>2, slot = t&3; source chunk = slot ^ ((row>>1)&3) = slot^((t>>3)&3).
    const int srow = t >> 2;
    const int scol = ((t & 3) ^ ((t >> 3) & 3)) * 8;
    const f16* gAh = Ah + (size_t)(row0 + srow) * Kd + scol;
    const f16* gAl = Al + (size_t)(row0 + srow) * Kd + scol;
    const f16* gBh = Bh + (size_t)(col0 + srow) * Kd + scol;
    const f16* gBl = Bl + (size_t)(col0 + srow) * Kd + scol;
    const size_t rskip = (size_t)128 * Kd;   // A rows 128..255, second GLDS round

    // Fragment read: row = sub16 + fr (fr = lane&15), slot = (lane>>4)^((row>>1)&3)
    // -> ((row>>1)&3) == (lane>>1)&3 since all row bases are multiples of 8.
    const int auo = (lane & 15) * 64 + (((lane >> 4) ^ ((lane >> 1) & 3)) << 4);
    const int abase = wm * 4096 + auo;   // wm*64 rows * 64 B
    const int bbase = wn * 4096 + auo;

#define STAGE(buf, ko) do { \
        char* const dA = ldsb + (buf) * 16384 + t * 16; \
        char* const dB = ldsb + 98304 + (buf) * 8192 + t * 16; \
        GLDS16(gAh + (ko), dA); \
        GLDS16(gAh + (ko) + rskip, dA + 8192); \
        GLDS16(gAl + (ko), dA + 49152); \
        GLDS16(gAl + (ko) + rskip, dA + 49152 + 8192); \
        GLDS16(gBh + (ko), dB); \
        GLDS16(gBl + (ko), dB + 24576); \
    } while (0)

    // prologue: stage tiles 0 and 1 (Kd >= 512 always here)
    STAGE(0, 0);
    STAGE(1, 32);

    int cur = 0, sbuf = 2;
    for (int k0 = 0; k0 < Kd; k0 += 32) {
        // issue prefetch for tile t+2 into the buffer freed by iter t-1
        if (k0 + 64 < Kd) STAGE(sbuf, k0 + 64);
        // counted wait: tile t complete; tiles t+1,t+2 stay in flight (T4)
        if (k0 + 64 < Kd)      asm volatile("s_waitcnt vmcnt(12)" ::: "memory");
        else if (k0 + 32 < Kd) asm volatile("s_waitcnt vmcnt(6)" ::: "memory");
        else                   asm volatile("s_waitcnt vmcnt(0)" ::: "memory");
        __builtin_amdgcn_s_barrier();

        const char* pa = ldsb + cur * 16384 + abase;
        const char* pb = ldsb + 98304 + cur * 8192 + bbase;

        // ---- phase 0: A frags (all mi) + B frags ni 0,1
        half8v fah[4], fal[4];
#pragma unroll
        for (int mi = 0; mi < 4; ++mi) {
            fah[mi] = *(const half8v*)(pa + mi * 1024);
            fal[mi] = *(const half8v*)(pa + 49152 + mi * 1024);
        }
        half8v fbh[2], fbl[2];
#pragma unroll
        for (int ni = 0; ni < 2; ++ni) {
            fbh[ni] = *(const half8v*)(pb + ni * 1024);
            fbl[ni] = *(const half8v*)(pb + 24576 + ni * 1024);
        }
        asm volatile("s_waitcnt lgkmcnt(0)" ::: "memory");
        __builtin_amdgcn_sched_barrier(0);
        __builtin_amdgcn_s_setprio(1);
#pragma unroll
        for (int ni = 0; ni < 2; ++ni)
#pragma unroll
            for (int mi = 0; mi < 4; ++mi) {
                acc_h[mi][ni] = __builtin_amdgcn_mfma_f32_16x16x32_f16(
                    fah[mi], fbh[ni], acc_h[mi][ni], 0, 0, 0);
                acc_l[mi][ni] = __builtin_amdgcn_mfma_f32_16x16x32_f16(
                    fah[mi], fbl[ni], acc_l[mi][ni], 0, 0, 0);
                acc_l[mi][ni] = __builtin_amdgcn_mfma_f32_16x16x32_f16(
                    fal[mi], fbh[ni], acc_l[mi][ni], 0, 0, 0);
            }
        __builtin_amdgcn_s_setprio(0);
        __builtin_amdgcn_s_barrier();

        // ---- phase 1: B frags ni 2,3 (A frags still live in regs)
#pragma unroll
        for (int ni = 0; ni < 2; ++ni) {
            fbh[ni] = *(const half8v*)(pb + (ni + 2) * 1024);
            fbl[ni] = *(const half8v*)(pb + 24576 + (ni + 2) * 1024);
        }
        asm volatile("s_waitcnt lgkmcnt(0)" ::: "memory");
        __builtin_amdgcn_sched_barrier(0);
        __builtin_amdgcn_s_setprio(1);
#pragma unroll
        for (int ni = 0; ni < 2; ++ni)
#pragma unroll
            for (int mi = 0; mi < 4; ++mi) {
                acc_h[mi][ni + 2] = __builtin_amdgcn_mfma_f32_16x16x32_f16(
                    fah[mi], fbh[ni], acc_h[mi][ni + 2], 0, 0, 0);
                acc_l[mi][ni + 2] = __builtin_amdgcn_mfma_f32_16x16x32_f16(
                    fah[mi], fbl[ni], acc_l[mi][ni + 2], 0, 0, 0);
                acc_l[mi][ni + 2] = __builtin_amdgcn_mfma_f32_16x16x32_f16(
                    fal[mi], fbh[ni], acc_l[mi][ni + 2], 0, 0, 0);
            }
        __builtin_amdgcn_s_setprio(0);
        // end-of-iter barrier: all waves done reading buffer cur ->
        // next iteration may stage into the buffer freed here
        __builtin_amdgcn_s_barrier();
        cur = (cur == 2) ? 0 : cur + 1;
        sbuf = (sbuf == 2) ? 0 : sbuf + 1;
    }
#undef STAGE

    const int cR = (lane >> 4) * 4;   // C/D: row = quad*4 + reg, col = lane&15
    const int cC = lane & 15;

    if (EPI == 0 || EPI == 2 || EPI == 3) {
#pragma unroll
        for (int ni = 0; ni < 4; ++ni) {
            const int col = col0 + wn * 64 + ni * 16 + cC;
            const float bb = bias[col];
#pragma unroll
            for (int mi = 0; mi < 4; ++mi)
#pragma unroll
                for (int r = 0; r < 4; ++r) {
                    const size_t row = row0 + wm * 64 + mi * 16 + cR + r;
                    float v = acc_h[mi][ni][r] + acc_l[mi][ni][r] * (1.f / 2048.f) + bb;
                    if (EPI == 2) v = fmaxf(v, 0.f);
                    if (EPI == 3) {
                        Cf[row * N + col] = v;
                    } else {
                        f16 vh, vl;
                        splitf(v, vh, vl);
                        Ch[row * N + col] = vh;
                        Cl[row * N + col] = vl;
                    }
                }
        }
    } else {  // EPI == 1: VQ tile argmin
#pragma unroll
        for (int mi = 0; mi < 4; ++mi)
#pragma unroll
            for (int r = 0; r < 4; ++r) {
                float bestv = 1e30f;
                int besti = 0;
#pragma unroll
                for (int ni = 0; ni < 4; ++ni) {
                    const int col = col0 + wn * 64 + ni * 16 + cC;
                    const float v = cnorm[col]
                        - 2.f * (acc_h[mi][ni][r] + acc_l[mi][ni][r] * (1.f / 2048.f));
                    if (v < bestv || (v == bestv && col < besti)) { bestv = v; besti = col; }
                }
#pragma unroll
                for (int m = 1; m < 16; m <<= 1) {
                    const float ov = __shfl_xor(bestv, m);
                    const int oi = __shfl_xor(besti, m);
                    if (ov < bestv || (ov == bestv && oi < besti)) { bestv = ov; besti = oi; }
                }
                if (cC == 0) {
                    const size_t row = row0 + wm * 64 + mi * 16 + cR + r;
                    cand_v[row * 8 + bx * 2 + wn] = bestv;
                    cand_i[row * 8 + bx * 2 + wn] = besti;
                }
            }
    }
}

// ---------------------------------------------------------------------------
// Fused prep: coalesced 32x32 LDS-tile transpose-splits for all 4 weights,
// vectorized codebook split, codebook row norms, sums init, x hi/lo split.
// ---------------------------------------------------------------------------
__global__ __launch_bounds__(256) void prep_k(
    const float* __restrict__ x, f16* __restrict__ xh, f16* __restrict__ xl,
    const float* __restrict__ enc_w1, f16* __restrict__ w1h, f16* __restrict__ w1l,
    const float* __restrict__ enc_w2, f16* __restrict__ w2h, f16* __restrict__ w2l,
    const float* __restrict__ codebook, f16* __restrict__ cbh, f16* __restrict__ cbl,
    const float* __restrict__ dec_w1, f16* __restrict__ dw1h, f16* __restrict__ dw1l,
    const float* __restrict__ dec_w2, f16* __restrict__ dw2h, f16* __restrict__ dw2l,
    float* __restrict__ cnorm, float* __restrict__ sums)
{
    __shared__ float tile[32][33];
    const int b = blockIdx.x;
    const int t = threadIdx.x;
    if (b < 2304) {
        // transpose-split W [K][N] -> Oh/Ol [N][K], 32x32 tiles
        const float* W; f16* Oh; f16* Ol; int K, N, tb;
        if (b < 768)       { W = enc_w1; Oh = w1h;  Ol = w1l;  K = 1024; N = 768;  tb = b; }
        else if (b < 1152) { W = enc_w2; Oh = w2h;  Ol = w2l;  K = 768;  N = 512;  tb = b - 768; }
        else if (b < 1536) { W = dec_w1; Oh = dw1h; Ol = dw1l; K = 512;  N = 768;  tb = b - 1152; }
        else               { W = dec_w2; Oh = dw2h; Ol = dw2l; K = 768;  N = 1024; tb = b - 1536; }
        const int ntx = N >> 5;
        const int tk = tb / ntx, tn = tb - tk * ntx;
        const int k0 = tk << 5, n0 = tn << 5;
        const int tx = t & 31, ty = t >> 5;
#pragma unroll
        for (int p = 0; p < 4; ++p)
            tile[ty + p * 8][tx] = W[(size_t)(k0 + ty + p * 8) * N + n0 + tx];
        __syncthreads();
#pragma unroll
        for (int p = 0; p < 4; ++p) {
            const int row = ty + p * 8;              // n offset in tile
            f16 h, l; splitf(tile[tx][row], h, l);   // [32][33]: conflict-free column read
            Oh[(size_t)(n0 + row) * K + k0 + tx] = h;
            Ol[(size_t)(n0 + row) * K + k0 + tx] = l;
        }
    } else if (b < 2432) {                // codebook split, vectorized (512x512)
        const size_t i = ((size_t)(b - 2304) * 256 + t) * 8;
        const float4 f0 = *(const float4*)(codebook + i);
        const float4 f1 = *(const float4*)(codebook + i + 4);
        const float fv[8] = {f0.x, f0.y, f0.z, f0.w, f1.x, f1.y, f1.z, f1.w};
        f16 hv[8] __attribute__((aligned(16)));
        f16 lv[8] __attribute__((aligned(16)));
#pragma unroll
        for (int j = 0; j < 8; ++j) splitf(fv[j], hv[j], lv[j]);
        *(half8v*)(cbh + i) = *(half8v*)hv;
        *(half8v*)(cbl + i) = *(half8v*)lv;
    } else if (b < 2560) {                // codebook row sum-squares
        const int lane = t & 63, wid = t >> 6;
        const size_t row = (size_t)(b - 2432) * 4 + wid;
        const float* p = codebook + row * 512;
        float s = 0.f;
#pragma unroll
        for (int e = 0; e < 8; ++e) { const float v = p[lane + e * 64]; s = fmaf(v, v, s); }
#pragma unroll
        for (int m = 1; m < 64; m <<= 1) s += __shfl_xor(s, m);
        if (lane == 0) cnorm[row] = s;
    } else if (b == 2560) {               // init loss accumulators
        if (t < 2) sums[t] = 0.f;
    } else {                              // x hi/lo split: blocks 2561..18944
        const size_t i = ((size_t)(b - 2561) * 256 + t) * 8;
        const float4 f0 = *(const float4*)(x + i);
        const float4 f1 = *(const float4*)(x + i + 4);
        const float fv[8] = {f0.x, f0.y, f0.z, f0.w, f1.x, f1.y, f1.z, f1.w};
        f16 hv[8] __attribute__((aligned(16)));
        f16 lv[8] __attribute__((aligned(16)));
#pragma unroll
        for (int j = 0; j < 8; ++j) splitf(fv[j], hv[j], lv[j]);
        *(half8v*)(xh + i) = *(half8v*)hv;
        *(half8v*)(xl + i) = *(half8v*)lv;
    }
}

// ---------------------------------------------------------------------------
// LayerNorm + ReLU on f16 hi/lo pair (in place), fp32 math, vectorized.
// ---------------------------------------------------------------------------
template<int H, bool ENORM>
__global__ __launch_bounds__(256) void ln_pair_k(
    f16* __restrict__ hi, f16* __restrict__ lo, const float* __restrict__ g,
    const float* __restrict__ b, float* __restrict__ enorm)
{
    constexpr int NCH = H / 8;
    constexpr int MAXC = (NCH + 63) / 64;
    const int lane = threadIdx.x & 63;
    const int wid = threadIdx.x >> 6;
    const size_t row = (size_t)blockIdx.x * 4 + wid;
    f16* ph = hi + row * H;
    f16* pl = lo + row * H;

    float h[MAXC * 8];
    float s = 0.f;
#pragma unroll
    for (int e = 0; e < MAXC; ++e) {
        const int c = lane + e * 64;
        if ((NCH % 64 == 0) || c < NCH) {
            const half8v vh = *(const half8v*)(ph + c * 8);
            const half8v vl = *(const half8v*)(pl + c * 8);
#pragma unroll
            for (int j = 0; j < 8; ++j) {
                h[e * 8 + j] = (float)vh[j] + (float)vl[j] * (1.f / 2048.f);
                s += h[e * 8 + j];
            }
        }
    }
#pragma unroll
    for (int m = 1; m < 64; m <<= 1) s += __shfl_xor(s, m);
    const float mu = s * (1.f / H);

    float vs = 0.f;
#pragma unroll
    for (int e = 0; e < MAXC; ++e) {
        const int c = lane + e * 64;
        if ((NCH % 64 == 0) || c < NCH) {
#pragma unroll
            for (int j = 0; j < 8; ++j) {
                const float d = h[e * 8 + j] - mu;
                vs = fmaf(d, d, vs);
            }
        }
    }
#pragma unroll
    for (int m = 1; m < 64; m <<= 1) vs += __shfl_xor(vs, m);
    const float rstd = rsqrtf(vs * (1.f / H) + 1e-5f);

    float q = 0.f;
#pragma unroll
    for (int e = 0; e < MAXC; ++e) {
        const int c = lane + e * 64;
        if ((NCH % 64 == 0) || c < NCH) {
            f16 oh[8] __attribute__((aligned(16)));
            f16 ol[8] __attribute__((aligned(16)));
#pragma unroll
            for (int j = 0; j < 8; ++j) {
                float o = (h[e * 8 + j] - mu) * rstd * g[c * 8 + j] + b[c * 8 + j];
                o = fmaxf(o, 0.f);
                splitf(o, oh[j], ol[j]);
                q = fmaf(o, o, q);
            }
            *(half8v*)(ph + c * 8) = *(half8v*)oh;
            *(half8v*)(pl + c * 8) = *(half8v*)ol;
        }
    }
    if (ENORM) {
#pragma unroll
        for (int m = 1; m < 64; m <<= 1) q += __shfl_xor(q, m);
        if (lane == 0) enorm[row] = q;
    }
}

__global__ __launch_bounds__(256) void vq_reduce_k(
    const float* __restrict__ cand_v, const int* __restrict__ cand_i,
    const float* __restrict__ enorm, float* __restrict__ out_idx_f,
    int* __restrict__ out_idx, float* __restrict__ commit_sum, int ntiles)
{
    const int tid = threadIdx.x;
    const int m = blockIdx.x * 256 + tid;
    float bv = cand_v[(size_t)m * ntiles];
    int bi = cand_i[(size_t)m * ntiles];
    for (int t = 1; t < ntiles; ++t) {
        const float v = cand_v[(size_t)m * ntiles + t];
        const int i = cand_i[(size_t)m * ntiles + t];
        if (v < bv || (v == bv && i < bi)) { bv = v; bi = i; }
    }
    out_idx_f[m] = (float)bi;
    out_idx[m] = bi;
    const float d2 = enorm[m] + bv;

    __shared__ float red[256];
    red[tid] = d2;
    __syncthreads();
    for (int s = 128; s > 0; s >>= 1) {
        if (tid < s) red[tid] += red[tid + s];
        __syncthreads();
    }
    if (tid == 0) atomicAdd(commit_sum, red[0]);
}

// recon: sum((V[idx[m]] - x[m])^2) over 8 tokens per block
__global__ __launch_bounds__(256) void recon_k(
    const int* __restrict__ idx, const float* __restrict__ V,
    const float* __restrict__ x, float* __restrict__ sum)
{
    const int t = threadIdx.x;
    float ls = 0.f;
#pragma unroll
    for (int tt = 0; tt < 8; ++tt) {
        const int m = blockIdx.x * 8 + tt;
        const int id = idx[m];
        const float4 v4 = ((const float4*)(V + (size_t)id * D_IN))[t];
        const float4 x4 = ((const float4*)(x + (size_t)m * D_IN))[t];
        const float d0 = v4.x - x4.x, d1 = v4.y - x4.y;
        const float d2 = v4.z - x4.z, d3 = v4.w - x4.w;
        ls = fmaf(d0, d0, ls); ls = fmaf(d1, d1, ls);
        ls = fmaf(d2, d2, ls); ls = fmaf(d3, d3, ls);
    }
    __shared__ float red[256];
    red[t] = ls;
    __syncthreads();
    for (int s = 128; s > 0; s >>= 1) {
        if (t < s) red[t] += red[t + s];
        __syncthreads();
    }
    if (t == 0) atomicAdd(sum, red[0]);
}

// pooled mean of codebook rows: two-stage for parallelism
__global__ __launch_bounds__(256) void pooled_part_k(
    const int* __restrict__ idx, const float* __restrict__ cb,
    float* __restrict__ part)
{
    const int b = blockIdx.x, c = blockIdx.y;   // grid (64, 8)
    const int d = threadIdx.x;
    float a0 = 0.f, a1 = 0.f;
    for (int t = c * 64; t < c * 64 + 64; ++t) {
        const int id = idx[b * 512 + t];
        a0 += cb[(size_t)id * 512 + d];
        a1 += cb[(size_t)id * 512 + d + 256];
    }
    part[((b * 8 + c) * 512) + d] = a0;
    part[((b * 8 + c) * 512) + d + 256] = a1;
}

__global__ __launch_bounds__(256) void pooled_fin_k(
    const float* __restrict__ part, float* __restrict__ pooled)
{
    const int b = blockIdx.x;
    const int d = threadIdx.x;
    float a0 = 0.f, a1 = 0.f;
#pragma unroll
    for (int c = 0; c < 8; ++c) {
        a0 += part[((b * 8 + c) * 512) + d];
        a1 += part[((b * 8 + c) * 512) + d + 256];
    }
    pooled[b * 512 + d] = a0 * (1.f / 512.f);
    pooled[b * 512 + d + 256] = a1 * (1.f / 512.f);
}

__global__ __launch_bounds__(256) void proj_k(
    const float* __restrict__ pooled, const float* __restrict__ w1,
    const float* __restrict__ b1, const float* __restrict__ w2,
    const float* __restrict__ b2, float* __restrict__ nproj)
{
    __shared__ float sp[512];
    __shared__ float sh[256];
    __shared__ float red[128];
    const int b = blockIdx.x, tid = threadIdx.x;
    sp[tid] = pooled[b * 512 + tid];
    sp[tid + 256] = pooled[b * 512 + tid + 256];
    __syncthreads();

    float acc = b1[tid];
    for (int k = 0; k < 512; ++k) acc = fmaf(sp[k], w1[k * 256 + tid], acc);
    sh[tid] = fmaxf(acc, 0.f);
    __syncthreads();

    float p = 0.f;
    if (tid < 128) {
        p = b2[tid];
        for (int k = 0; k < 256; ++k) p = fmaf(sh[k], w2[k * 128 + tid], p);
        red[tid] = p * p;
    }
    __syncthreads();
    for (int s = 64; s > 0; s >>= 1) {
        if (tid < s) red[tid] += red[tid + s];
        __syncthreads();
    }
    if (tid < 128) {
        const float nrm = fmaxf(sqrtf(red[0]), 1e-12f);
        nproj[b * 128 + tid] = p / nrm;
    }
}

// one block per row i of the 64x64 sim matrix; log-softmax diag term
__global__ __launch_bounds__(256) void sim_k(
    const float* __restrict__ nproj, float* __restrict__ rowterm)
{
    __shared__ float ri[128];
    __shared__ float srow[64];
    const int i = blockIdx.x, t = threadIdx.x;
    if (t < 128) ri[t] = nproj[i * 128 + t];
    __syncthreads();

    const int j = t >> 2, q = t & 3;
    float d = 0.f;
    for (int k = q * 32; k < q * 32 + 32; ++k)
        d = fmaf(ri[k], nproj[j * 128 + k], d);
    d += __shfl_xor(d, 1);
    d += __shfl_xor(d, 2);
    if (q == 0) srow[j] = d * 10.f;   // / TEMP
    __syncthreads();

    if (t < 64) {
        float v = srow[t];
        float mx = v;
#pragma unroll
        for (int m = 1; m < 64; m <<= 1) mx = fmaxf(mx, __shfl_xor(mx, m));
        float e = expf(v - mx);
#pragma unroll
        for (int m = 1; m < 64; m <<= 1) e += __shfl_xor(e, m);
        if (t == 0) rowterm[i] = srow[i] - (mx + logf(e));
    }
}

__global__ __launch_bounds__(64) void final_k(
    const float* __restrict__ rowterm, const float* __restrict__ sums,
    float* __restrict__ out5)
{
    const int t = threadIdx.x;
    float c = rowterm[t];
#pragma unroll
    for (int m = 1; m < 64; m <<= 1) c += __shfl_xor(c, m);
    if (t == 0) {
        const float contr = -c / 64.f;
        const float recon = sums[0] / ((float)BT_TOK * (float)D_IN);
        const float commit = sums[1] / ((float)BT_TOK * (float)H2D);
        const float cbl = commit;
        const float total = recon * 1.0f + commit * 1.0f + cbl * 0.25f + contr * 0.5f;
        out5[0] = total;
        out5[1] = recon;
        out5[2] = commit;
        out5[3] = cbl;
        out5[4] = contr;
    }
}

extern "C" void kernel_launch(void* const* d_in, const int* in_sizes, int n_in,
                              void* d_out, int out_size, void* d_ws, size_t ws_size,
                              hipStream_t stream)
{
    const float* x       = (const float*)d_in[0];
    const float* enc_w1  = (const float*)d_in[1];
    const float* enc_b1  = (const float*)d_in[2];
    const float* ln1_g   = (const float*)d_in[3];
    const float* ln1_b   = (const float*)d_in[4];
    const float* enc_w2  = (const float*)d_in[5];
    const float* enc_b2  = (const float*)d_in[6];
    const float* ln2_g   = (const float*)d_in[7];
    const float* ln2_b   = (const float*)d_in[8];
    const float* codebook= (const float*)d_in[9];
    const float* dec_w1  = (const float*)d_in[10];
    const float* dec_b1  = (const float*)d_in[11];
    const float* dec_w2  = (const float*)d_in[12];
    const float* dec_b2  = (const float*)d_in[13];
    const float* proj_w1 = (const float*)d_in[14];
    const float* proj_b1 = (const float*)d_in[15];
    const float* proj_w2 = (const float*)d_in[16];
    const float* proj_b2 = (const float*)d_in[17];
    float* out = (float*)d_out;

    char* wsb = (char*)d_ws;
    size_t off = 0;
    auto alloc = [&](size_t bytes) {
        void* p = wsb + off;
        off += (bytes + 255) & ~(size_t)255;
        return p;
    };

    f16* xh   = (f16*)alloc((size_t)BT_TOK * D_IN * 2);   // x hi/lo split
    f16* xl   = (f16*)alloc((size_t)BT_TOK * D_IN * 2);
    f16* h1h  = (f16*)alloc((size_t)BT_TOK * H1D * 2);
    f16* h1l  = (f16*)alloc((size_t)BT_TOK * H1D * 2);
    // ench/encl alias xh/xl: xh/xl dead after GEMM1, ench written by GEMM2.
    f16* ench = xh;
    f16* encl = xl;
    f16* w1h  = (f16*)alloc((size_t)H1D * D_IN * 2);
    f16* w1l  = (f16*)alloc((size_t)H1D * D_IN * 2);
    f16* w2h  = (f16*)alloc((size_t)H2D * H1D * 2);
    f16* w2l  = (f16*)alloc((size_t)H2D * H1D * 2);
    f16* cbh  = (f16*)alloc((size_t)KCB * H2D * 2);
    f16* cbl  = (f16*)alloc((size_t)KCB * H2D * 2);
    f16* dw1h = (f16*)alloc((size_t)H1D * H2D * 2);   // [768][512]
    f16* dw1l = (f16*)alloc((size_t)H1D * H2D * 2);
    f16* dw2h = (f16*)alloc((size_t)D_IN * H1D * 2);  // [1024][768]
    f16* dw2l = (f16*)alloc((size_t)D_IN * H1D * 2);
    f16* Uh   = (f16*)alloc((size_t)KCB * H1D * 2);   // relu(cb@W1+b1) pair
    f16* Ul   = (f16*)alloc((size_t)KCB * H1D * 2);
    float* Vf = (float*)alloc((size_t)KCB * D_IN * 4); // per-code decoded rows
    float* cnorm  = (float*)alloc(KCB * 4);
    float* enorm  = (float*)alloc(BT_TOK * 4);
    float* cand_v = (float*)alloc((size_t)BT_TOK * 8 * 4);
    int*   cand_i = (int*)alloc((size_t)BT_TOK * 8 * 4);
    int*   idxbuf = (int*)alloc(BT_TOK * 4);
    float* ppart  = (float*)alloc(64 * 8 * 512 * 4);
    float* pooled = (float*)alloc(64 * 512 * 4);
    float* nproj  = (float*)alloc(64 * 128 * 4);
    float* rowterm= (float*)alloc(64 * 4);
    float* sums   = (float*)alloc(2 * 4);

    const dim3 blk(256);
    const dim3 gblk(512);

    // prep: weight transpose-splits + codebook split + cnorm + sums + x split
    prep_k<<<dim3(18945), blk, 0, stream>>>(
        x, xh, xl, enc_w1, w1h, w1l, enc_w2, w2h, w2l, codebook, cbh, cbl,
        dec_w1, dw1h, dw1l, dec_w2, dw2h, dw2l, cnorm, sums);

    // per-code decoder tables (decoder input has only 512 distinct values):
    // U = relu(cb @ dec_w1 + b1)  [512 x 768];  V = U @ dec_w2 + b2 [512 x 1024]
    sgemm_k<2><<<dim3(H1D / 128, KCB / 256), gblk, 0, stream>>>(
        cbh, cbl, dw1h, dw1l, dec_b1, Uh, Ul, nullptr,
        nullptr, nullptr, nullptr, H1D, H2D);
    sgemm_k<3><<<dim3(D_IN / 128, KCB / 256), gblk, 0, stream>>>(
        Uh, Ul, dw2h, dw2l, dec_b2, nullptr, nullptr, Vf,
        nullptr, nullptr, nullptr, D_IN, H1D);

    // encoder layer 1: h1 = x @ enc_w1 + b1
    sgemm_k<0><<<dim3(H1D / 128, BT_TOK / 256), gblk, 0, stream>>>(
        xh, xl, w1h, w1l, enc_b1, h1h, h1l, nullptr,
        nullptr, nullptr, nullptr, H1D, D_IN);
    ln_pair_k<H1D, false><<<dim3(BT_TOK / 4), blk, 0, stream>>>(h1h, h1l, ln1_g, ln1_b, nullptr);

    // encoder layer 2: enc = h1 @ enc_w2 + b2
    sgemm_k<0><<<dim3(H2D / 128, BT_TOK / 256), gblk, 0, stream>>>(
        h1h, h1l, w2h, w2l, enc_b2, ench, encl, nullptr,
        nullptr, nullptr, nullptr, H2D, H1D);
    ln_pair_k<H2D, true><<<dim3(BT_TOK / 4), blk, 0, stream>>>(ench, encl, ln2_g, ln2_b, enorm);

    // VQ scores + tile argmin (fp32-equivalent via split)
    sgemm_k<1><<<dim3(KCB / 128, BT_TOK / 256), gblk, 0, stream>>>(
        ench, encl, cbh, cbl, nullptr, nullptr, nullptr, nullptr,
        cnorm, cand_v, cand_i, KCB, H2D);
    vq_reduce_k<<<dim3(BT_TOK / 256), blk, 0, stream>>>(
        cand_v, cand_i, enorm, out, idxbuf, sums + 1, 8);

    // recon loss via per-code decoded table (exact decoder collapse)
    recon_k<<<dim3(BT_TOK / 8), blk, 0, stream>>>(idxbuf, Vf, x, sums);

    pooled_part_k<<<dim3(64, 8), blk, 0, stream>>>(idxbuf, codebook, ppart);
    pooled_fin_k<<<dim3(64), blk, 0, stream>>>(ppart, pooled);
    proj_k<<<dim3(64), blk, 0, stream>>>(pooled, proj_w1, proj_b1, proj_w2, proj_b2, nproj);
    sim_k<<<dim3(64), blk, 0, stream>>>(nproj, rowterm);
    final_k<<<dim3(1), dim3(64), 0, stream>>>(rowterm, sums, out + BT_TOK);
}

// Round 4
// 739.043 us; speedup vs baseline: 1.0851x; 1.0851x over previous
//
#include <hip/hip_runtime.h>
#include <math.h>

#define BT_TOK 32768
#define D_IN   1024
#define H1D    768
#define H2D    512
#define KCB    512

typedef _Float16 f16;
typedef _Float16 half8v __attribute__((ext_vector_type(8)));
typedef float f32x4 __attribute__((ext_vector_type(4)));

#define GLDS16(g, l) \
    __builtin_amdgcn_global_load_lds((const __attribute__((address_space(1))) void*)(g), \
                                     (__attribute__((address_space(3))) void*)(l), 16, 0, 0)

// split convention: hi = f16(v), lo = f16((v-hi)*2048); v ~= hi + lo/2048
__device__ __forceinline__ void splitf(float v, f16& h, f16& l) {
    h = (f16)v;
    l = (f16)((v - (float)h) * 2048.f);
}

// ---------------------------------------------------------------------------
// Split-FP16 MFMA GEMM (R2 schedule: BM=256 x BN=128, BK=32, 512 thr = 8
// waves 4Mx2N, per-wave 64x64, double-buffered 96 KiB LDS, 2 MFMA phases per
// K-tile, drain vmcnt(0) after phase-1 MFMA cover).
// AF32=true (GEMM1): A is raw fp32; staged to LDS as 128-B rows via
//   global_load_lds with 16-B-granule XOR swizzle slot = g ^ (row&7) on BOTH
//   the staging source and the frag read (involution; 2 lanes/bank-quad =
//   minimal aliasing). Frags read as 2x ds_read_b128 of f32 and split to the
//   f16 hi/lo pair IN-REGISTER (bit-identical to prep's splitf) - removes
//   the 384 MB x-split prep pass entirely.
// AF32=false: A is a pre-split f16 pair, 64-B rows, chunk swizzle
//   slot = s ^ ((row>>1)&3) (0-conflict, verified round 1).
// EPI 0: +bias -> f16 pair. 1: VQ tile-argmin. 2: +bias,relu -> f16 pair.
// EPI 3: +bias -> fp32.
// ---------------------------------------------------------------------------
template<int EPI, bool AF32>
__global__ __launch_bounds__(512, 2) void sgemm_k(
    const float* __restrict__ Af,
    const f16* __restrict__ Ah, const f16* __restrict__ Al,
    const f16* __restrict__ Bh, const f16* __restrict__ Bl,
    const float* __restrict__ bias,
    f16* __restrict__ Ch, f16* __restrict__ Cl,
    float* __restrict__ Cf,
    const float* __restrict__ cnorm,
    float* __restrict__ cand_v, int* __restrict__ cand_i,
    int N, int Kd)
{
    // AF32: [0,64K) sAf 2x32K | [64K,80K) sBh 2x8K | [80K,96K) sBl 2x8K
    // f16 : [0,32K) sAh 2x16K | [32K,64K) sAl | same B layout
    __shared__ __align__(16) char lds[98304];
    char* const ldsb = lds;

    const int t = threadIdx.x;
    const int lane = t & 63, wave = t >> 6;
    const int wm = wave & 3, wn = wave >> 2;

    const int nwg = gridDim.x * gridDim.y;
    int flat = blockIdx.y * gridDim.x + blockIdx.x;
    if ((nwg & 7) == 0) flat = (flat & 7) * (nwg >> 3) + (flat >> 3);
    const int bx = flat % gridDim.x;
    const int by = flat / gridDim.x;
    const int row0 = by * 256, col0 = bx * 128;

    f32x4 acc_h[4][4], acc_l[4][4];
#pragma unroll
    for (int i = 0; i < 4; ++i)
#pragma unroll
        for (int j = 0; j < 4; ++j) {
            acc_h[i][j] = (f32x4){0.f, 0.f, 0.f, 0.f};
            acc_l[i][j] = (f32x4){0.f, 0.f, 0.f, 0.f};
        }

    // ---- staging pointers
    // B (f16 pair, 64-B rows): row = t>>2, slot = t&3, src chunk = slot^((t>>3)&3)
    const int srow = t >> 2;
    const int scol = ((t & 3) ^ ((t >> 3) & 3)) * 8;
    const f16* gBh = Bh + (size_t)(col0 + srow) * Kd + scol;
    const f16* gBl = Bl + (size_t)(col0 + srow) * Kd + scol;
    // A fp32 (AF32): 128-B rows, round covers 64 rows; row = t>>3, granule
    // slot = t&7 holds global granule (t&7)^((t>>3)&7)
    const float* gAf = AF32 ?
        (Af + (size_t)(row0 + (t >> 3)) * Kd + (((t & 7) ^ ((t >> 3) & 7)) << 2)) : nullptr;
    // A f16 pair (non-AF32): 64-B rows like B
    const f16* gAh = AF32 ? nullptr : (Ah + (size_t)(row0 + srow) * Kd + scol);
    const f16* gAl = AF32 ? nullptr : (Al + (size_t)(row0 + srow) * Kd + scol);
    const size_t rskip = (size_t)128 * Kd;

    // ---- fragment read addressing
    const int fr = lane & 15;
    const int c0 = lane >> 4;
    // f16 path (64-B rows): slot = c0 ^ ((row>>1)&3) -> lane-constant
    const int fko = ((c0 ^ ((lane >> 1) & 3)) << 4);
    const int auo = fr * 64 + fko;
    const int abase16 = wm * 4096 + auo;
    const int bbase = wn * 4096 + auo;
    // f32 path (128-B rows): granule g ^ (row&7), row&7 == fr&7
    const int fr7 = lane & 7;
    const int offA1 = (((2 * c0) ^ fr7) << 4);
    const int offA2 = (((2 * c0 + 1) ^ fr7) << 4);
    const int abase32 = (wm * 64 + fr) * 128;

    const int aBufSz = AF32 ? 32768 : 16384;
    const int bBase  = AF32 ? 65536 : 65536;   // B region start
    const int alOff  = 32768;                   // sAl offset (f16 path)

#define STAGE(buf, ko) do { \
        char* const dB = ldsb + bBase + (buf) * 8192 + t * 16; \
        GLDS16(gBh + (ko), dB); \
        GLDS16(gBl + (ko), dB + 16384); \
        if (AF32) { \
            char* const dA = ldsb + (buf) * 32768 + t * 16; \
            const float* ga = gAf + (ko); \
            GLDS16(ga, dA); \
            GLDS16(ga + (size_t)64 * Kd, dA + 8192); \
            GLDS16(ga + (size_t)128 * Kd, dA + 16384); \
            GLDS16(ga + (size_t)192 * Kd, dA + 24576); \
        } else { \
            char* const dA = ldsb + (buf) * 16384 + t * 16; \
            GLDS16(gAh + (ko), dA); \
            GLDS16(gAh + (ko) + rskip, dA + 8192); \
            GLDS16(gAl + (ko), dA + alOff); \
            GLDS16(gAl + (ko) + rskip, dA + alOff + 8192); \
        } \
    } while (0)

    // prologue
    STAGE(0, 0);
    asm volatile("s_waitcnt vmcnt(0)" ::: "memory");
    __builtin_amdgcn_s_barrier();

    int cur = 0;
    for (int k0 = 0; k0 < Kd; k0 += 32) {
        const char* pa = ldsb + cur * aBufSz;
        const char* pb = ldsb + bBase + cur * 8192 + bbase;

        // ---- phase 0: A raw reads + B frags ni 0,1; prefetch next tile
        f32x4 ra[4], rb[4];          // AF32 raw
        half8v fah[4], fal[4];
        if (AF32) {
#pragma unroll
            for (int mi = 0; mi < 4; ++mi) {
                ra[mi] = *(const f32x4*)(pa + abase32 + mi * 2048 + offA1);
                rb[mi] = *(const f32x4*)(pa + abase32 + mi * 2048 + offA2);
            }
        } else {
#pragma unroll
            for (int mi = 0; mi < 4; ++mi) {
                fah[mi] = *(const half8v*)(pa + abase16 + mi * 1024);
                fal[mi] = *(const half8v*)(pa + alOff + abase16 + mi * 1024);
            }
        }
        half8v fbh[2], fbl[2];
#pragma unroll
        for (int ni = 0; ni < 2; ++ni) {
            fbh[ni] = *(const half8v*)(pb + ni * 1024);
            fbl[ni] = *(const half8v*)(pb + 16384 + ni * 1024);
        }
        if (k0 + 32 < Kd) STAGE(cur ^ 1, k0 + 32);
        __builtin_amdgcn_s_barrier();
        asm volatile("s_waitcnt lgkmcnt(0)" ::: "memory");
        __builtin_amdgcn_sched_barrier(0);
        if (AF32) {   // in-register split (bit-identical to prep splitf)
#pragma unroll
            for (int mi = 0; mi < 4; ++mi) {
#pragma unroll
                for (int j = 0; j < 4; ++j) {
                    f16 h, l;
                    splitf(ra[mi][j], h, l); fah[mi][j] = h; fal[mi][j] = l;
                    splitf(rb[mi][j], h, l); fah[mi][j + 4] = h; fal[mi][j + 4] = l;
                }
            }
        }
        __builtin_amdgcn_s_setprio(1);
#pragma unroll
        for (int ni = 0; ni < 2; ++ni)
#pragma unroll
            for (int mi = 0; mi < 4; ++mi) {
                acc_h[mi][ni] = __builtin_amdgcn_mfma_f32_16x16x32_f16(
                    fah[mi], fbh[ni], acc_h[mi][ni], 0, 0, 0);
                acc_l[mi][ni] = __builtin_amdgcn_mfma_f32_16x16x32_f16(
                    fah[mi], fbl[ni], acc_l[mi][ni], 0, 0, 0);
                acc_l[mi][ni] = __builtin_amdgcn_mfma_f32_16x16x32_f16(
                    fal[mi], fbh[ni], acc_l[mi][ni], 0, 0, 0);
            }
        __builtin_amdgcn_s_setprio(0);
        __builtin_amdgcn_s_barrier();

        // ---- phase 1: B frags ni 2,3 (A frags live in regs)
#pragma unroll
        for (int ni = 0; ni < 2; ++ni) {
            fbh[ni] = *(const half8v*)(pb + (ni + 2) * 1024);
            fbl[ni] = *(const half8v*)(pb + 16384 + (ni + 2) * 1024);
        }
        __builtin_amdgcn_s_barrier();
        asm volatile("s_waitcnt lgkmcnt(0)" ::: "memory");
        __builtin_amdgcn_sched_barrier(0);
        __builtin_amdgcn_s_setprio(1);
#pragma unroll
        for (int ni = 0; ni < 2; ++ni)
#pragma unroll
            for (int mi = 0; mi < 4; ++mi) {
                acc_h[mi][ni + 2] = __builtin_amdgcn_mfma_f32_16x16x32_f16(
                    fah[mi], fbh[ni], acc_h[mi][ni + 2], 0, 0, 0);
                acc_l[mi][ni + 2] = __builtin_amdgcn_mfma_f32_16x16x32_f16(
                    fah[mi], fbl[ni], acc_l[mi][ni + 2], 0, 0, 0);
                acc_l[mi][ni + 2] = __builtin_amdgcn_mfma_f32_16x16x32_f16(
                    fal[mi], fbh[ni], acc_l[mi][ni + 2], 0, 0, 0);
            }
        __builtin_amdgcn_s_setprio(0);
        asm volatile("s_waitcnt vmcnt(0)" ::: "memory");
        __builtin_amdgcn_s_barrier();
        cur ^= 1;
    }
#undef STAGE

    const int cR = (lane >> 4) * 4;   // C/D: row = quad*4 + reg, col = lane&15
    const int cC = lane & 15;

    if (EPI == 0 || EPI == 2 || EPI == 3) {
#pragma unroll
        for (int ni = 0; ni < 4; ++ni) {
            const int col = col0 + wn * 64 + ni * 16 + cC;
            const float bb = bias[col];
#pragma unroll
            for (int mi = 0; mi < 4; ++mi)
#pragma unroll
                for (int r = 0; r < 4; ++r) {
                    const size_t row = row0 + wm * 64 + mi * 16 + cR + r;
                    float v = acc_h[mi][ni][r] + acc_l[mi][ni][r] * (1.f / 2048.f) + bb;
                    if (EPI == 2) v = fmaxf(v, 0.f);
                    if (EPI == 3) {
                        Cf[row * N + col] = v;
                    } else {
                        f16 vh, vl;
                        splitf(v, vh, vl);
                        Ch[row * N + col] = vh;
                        Cl[row * N + col] = vl;
                    }
                }
        }
    } else {  // EPI == 1: VQ tile argmin
#pragma unroll
        for (int mi = 0; mi < 4; ++mi)
#pragma unroll
            for (int r = 0; r < 4; ++r) {
                float bestv = 1e30f;
                int besti = 0;
#pragma unroll
                for (int ni = 0; ni < 4; ++ni) {
                    const int col = col0 + wn * 64 + ni * 16 + cC;
                    const float v = cnorm[col]
                        - 2.f * (acc_h[mi][ni][r] + acc_l[mi][ni][r] * (1.f / 2048.f));
                    if (v < bestv || (v == bestv && col < besti)) { bestv = v; besti = col; }
                }
#pragma unroll
                for (int m = 1; m < 16; m <<= 1) {
                    const float ov = __shfl_xor(bestv, m);
                    const int oi = __shfl_xor(besti, m);
                    if (ov < bestv || (ov == bestv && oi < besti)) { bestv = ov; besti = oi; }
                }
                if (cC == 0) {
                    const size_t row = row0 + wm * 64 + mi * 16 + cR + r;
                    cand_v[row * 8 + bx * 2 + wn] = bestv;
                    cand_i[row * 8 + bx * 2 + wn] = besti;
                }
            }
    }
}

// ---------------------------------------------------------------------------
// Fused prep: coalesced 32x32 LDS-tile transpose-splits for all 4 weights,
// vectorized codebook split, codebook row norms, sums init. (x split REMOVED
// - GEMM1 now stages fp32 x directly.)
// ---------------------------------------------------------------------------
__global__ __launch_bounds__(256) void prep_k(
    const float* __restrict__ enc_w1, f16* __restrict__ w1h, f16* __restrict__ w1l,
    const float* __restrict__ enc_w2, f16* __restrict__ w2h, f16* __restrict__ w2l,
    const float* __restrict__ codebook, f16* __restrict__ cbh, f16* __restrict__ cbl,
    const float* __restrict__ dec_w1, f16* __restrict__ dw1h, f16* __restrict__ dw1l,
    const float* __restrict__ dec_w2, f16* __restrict__ dw2h, f16* __restrict__ dw2l,
    float* __restrict__ cnorm, float* __restrict__ sums)
{
    __shared__ float tile[32][33];
    const int b = blockIdx.x;
    const int t = threadIdx.x;
    if (b < 2304) {
        // transpose-split W [K][N] -> Oh/Ol [N][K], 32x32 tiles
        const float* W; f16* Oh; f16* Ol; int K, N, tb;
        if (b < 768)       { W = enc_w1; Oh = w1h;  Ol = w1l;  K = 1024; N = 768;  tb = b; }
        else if (b < 1152) { W = enc_w2; Oh = w2h;  Ol = w2l;  K = 768;  N = 512;  tb = b - 768; }
        else if (b < 1536) { W = dec_w1; Oh = dw1h; Ol = dw1l; K = 512;  N = 768;  tb = b - 1152; }
        else               { W = dec_w2; Oh = dw2h; Ol = dw2l; K = 768;  N = 1024; tb = b - 1536; }
        const int ntx = N >> 5;
        const int tk = tb / ntx, tn = tb - tk * ntx;
        const int k0 = tk << 5, n0 = tn << 5;
        const int tx = t & 31, ty = t >> 5;
#pragma unroll
        for (int p = 0; p < 4; ++p)
            tile[ty + p * 8][tx] = W[(size_t)(k0 + ty + p * 8) * N + n0 + tx];
        __syncthreads();
#pragma unroll
        for (int p = 0; p < 4; ++p) {
            const int row = ty + p * 8;
            f16 h, l; splitf(tile[tx][row], h, l);
            Oh[(size_t)(n0 + row) * K + k0 + tx] = h;
            Ol[(size_t)(n0 + row) * K + k0 + tx] = l;
        }
    } else if (b < 2432) {                // codebook split, vectorized (512x512)
        const size_t i = ((size_t)(b - 2304) * 256 + t) * 8;
        const float4 f0 = *(const float4*)(codebook + i);
        const float4 f1 = *(const float4*)(codebook + i + 4);
        const float fv[8] = {f0.x, f0.y, f0.z, f0.w, f1.x, f1.y, f1.z, f1.w};
        f16 hv[8] __attribute__((aligned(16)));
        f16 lv[8] __attribute__((aligned(16)));
#pragma unroll
        for (int j = 0; j < 8; ++j) splitf(fv[j], hv[j], lv[j]);
        *(half8v*)(cbh + i) = *(half8v*)hv;
        *(half8v*)(cbl + i) = *(half8v*)lv;
    } else if (b < 2560) {                // codebook row sum-squares
        const int lane = t & 63, wid = t >> 6;
        const size_t row = (size_t)(b - 2432) * 4 + wid;
        const float* p = codebook + row * 512;
        float s = 0.f;
#pragma unroll
        for (int e = 0; e < 8; ++e) { const float v = p[lane + e * 64]; s = fmaf(v, v, s); }
#pragma unroll
        for (int m = 1; m < 64; m <<= 1) s += __shfl_xor(s, m);
        if (lane == 0) cnorm[row] = s;
    } else {                              // init loss accumulators
        if (t < 2) sums[t] = 0.f;
    }
}

// ---------------------------------------------------------------------------
// LayerNorm + ReLU on f16 hi/lo pair (in place), fp32 math, vectorized.
// ---------------------------------------------------------------------------
template<int H, bool ENORM>
__global__ __launch_bounds__(256) void ln_pair_k(
    f16* __restrict__ hi, f16* __restrict__ lo, const float* __restrict__ g,
    const float* __restrict__ b, float* __restrict__ enorm)
{
    constexpr int NCH = H / 8;
    constexpr int MAXC = (NCH + 63) / 64;
    const int lane = threadIdx.x & 63;
    const int wid = threadIdx.x >> 6;
    const size_t row = (size_t)blockIdx.x * 4 + wid;
    f16* ph = hi + row * H;
    f16* pl = lo + row * H;

    float h[MAXC * 8];
    float s = 0.f;
#pragma unroll
    for (int e = 0; e < MAXC; ++e) {
        const int c = lane + e * 64;
        if ((NCH % 64 == 0) || c < NCH) {
            const half8v vh = *(const half8v*)(ph + c * 8);
            const half8v vl = *(const half8v*)(pl + c * 8);
#pragma unroll
            for (int j = 0; j < 8; ++j) {
                h[e * 8 + j] = (float)vh[j] + (float)vl[j] * (1.f / 2048.f);
                s += h[e * 8 + j];
            }
        }
    }
#pragma unroll
    for (int m = 1; m < 64; m <<= 1) s += __shfl_xor(s, m);
    const float mu = s * (1.f / H);

    float vs = 0.f;
#pragma unroll
    for (int e = 0; e < MAXC; ++e) {
        const int c = lane + e * 64;
        if ((NCH % 64 == 0) || c < NCH) {
#pragma unroll
            for (int j = 0; j < 8; ++j) {
                const float d = h[e * 8 + j] - mu;
                vs = fmaf(d, d, vs);
            }
        }
    }
#pragma unroll
    for (int m = 1; m < 64; m <<= 1) vs += __shfl_xor(vs, m);
    const float rstd = rsqrtf(vs * (1.f / H) + 1e-5f);

    float q = 0.f;
#pragma unroll
    for (int e = 0; e < MAXC; ++e) {
        const int c = lane + e * 64;
        if ((NCH % 64 == 0) || c < NCH) {
            f16 oh[8] __attribute__((aligned(16)));
            f16 ol[8] __attribute__((aligned(16)));
#pragma unroll
            for (int j = 0; j < 8; ++j) {
                float o = (h[e * 8 + j] - mu) * rstd * g[c * 8 + j] + b[c * 8 + j];
                o = fmaxf(o, 0.f);
                splitf(o, oh[j], ol[j]);
                q = fmaf(o, o, q);
            }
            *(half8v*)(ph + c * 8) = *(half8v*)oh;
            *(half8v*)(pl + c * 8) = *(half8v*)ol;
        }
    }
    if (ENORM) {
#pragma unroll
        for (int m = 1; m < 64; m <<= 1) q += __shfl_xor(q, m);
        if (lane == 0) enorm[row] = q;
    }
}

// ---------------------------------------------------------------------------
// Merged VQ-reduce + recon: 256 blocks x 128 tokens. Part 1: final argmin
// across the 8 tile candidates + commit partial. Part 2: recon loss for the
// same tokens using the freshly computed idx (from LDS).
// ---------------------------------------------------------------------------
__global__ __launch_bounds__(256) void vqrr_k(
    const float* __restrict__ cand_v, const int* __restrict__ cand_i,
    const float* __restrict__ enorm, float* __restrict__ out_idx_f,
    int* __restrict__ out_idx, float* __restrict__ sums,
    const float* __restrict__ V, const float* __restrict__ x)
{
    __shared__ int sidx[128];
    __shared__ float red[256];
    const int tid = threadIdx.x;
    const int blk = blockIdx.x;

    float commit = 0.f;
    if (tid < 128) {
        const int m = blk * 128 + tid;
        float bv = cand_v[(size_t)m * 8];
        int bi = cand_i[(size_t)m * 8];
#pragma unroll
        for (int tt = 1; tt < 8; ++tt) {
            const float v = cand_v[(size_t)m * 8 + tt];
            const int i = cand_i[(size_t)m * 8 + tt];
            if (v < bv || (v == bv && i < bi)) { bv = v; bi = i; }
        }
        out_idx_f[m] = (float)bi;
        out_idx[m] = bi;
        sidx[tid] = bi;
        commit = enorm[m] + bv;
    }
    red[tid] = (tid < 128) ? commit : 0.f;
    __syncthreads();
    for (int s = 128; s > 0; s >>= 1) {
        if (tid < s) red[tid] += red[tid + s];
        __syncthreads();
    }
    if (tid == 0) atomicAdd(sums + 1, red[0]);
    __syncthreads();

    // recon part: 128 tokens x 1024 dims, thread = float4 slot
    float ls = 0.f;
    for (int tt = 0; tt < 128; ++tt) {
        const int id = sidx[tt];
        const float4 v4 = ((const float4*)(V + (size_t)id * D_IN))[tid];
        const float4 x4 = ((const float4*)(x + (size_t)(blk * 128 + tt) * D_IN))[tid];
        const float d0 = v4.x - x4.x, d1 = v4.y - x4.y;
        const float d2 = v4.z - x4.z, d3 = v4.w - x4.w;
        ls = fmaf(d0, d0, ls); ls = fmaf(d1, d1, ls);
        ls = fmaf(d2, d2, ls); ls = fmaf(d3, d3, ls);
    }
    __syncthreads();
    red[tid] = ls;
    __syncthreads();
    for (int s = 128; s > 0; s >>= 1) {
        if (tid < s) red[tid] += red[tid + s];
        __syncthreads();
    }
    if (tid == 0) atomicAdd(sums, red[0]);
}

// pooled mean of codebook rows: two-stage for parallelism
__global__ __launch_bounds__(256) void pooled_part_k(
    const int* __restrict__ idx, const float* __restrict__ cb,
    float* __restrict__ part)
{
    const int b = blockIdx.x, c = blockIdx.y;   // grid (64, 8)
    const int d = threadIdx.x;
    float a0 = 0.f, a1 = 0.f;
    for (int t = c * 64; t < c * 64 + 64; ++t) {
        const int id = idx[b * 512 + t];
        a0 += cb[(size_t)id * 512 + d];
        a1 += cb[(size_t)id * 512 + d + 256];
    }
    part[((b * 8 + c) * 512) + d] = a0;
    part[((b * 8 + c) * 512) + d + 256] = a1;
}

// proj (reads ppart directly, folds pooled_fin)
__global__ __launch_bounds__(256) void proj_k(
    const float* __restrict__ part, const float* __restrict__ w1,
    const float* __restrict__ b1, const float* __restrict__ w2,
    const float* __restrict__ b2, float* __restrict__ nproj)
{
    __shared__ float sp[512];
    __shared__ float sh[256];
    __shared__ float red[128];
    const int b = blockIdx.x, tid = threadIdx.x;
    {
        float a0 = 0.f, a1 = 0.f;
#pragma unroll
        for (int c = 0; c < 8; ++c) {
            a0 += part[((b * 8 + c) * 512) + tid];
            a1 += part[((b * 8 + c) * 512) + tid + 256];
        }
        sp[tid] = a0 * (1.f / 512.f);
        sp[tid + 256] = a1 * (1.f / 512.f);
    }
    __syncthreads();

    float acc = b1[tid];
    for (int k = 0; k < 512; ++k) acc = fmaf(sp[k], w1[k * 256 + tid], acc);
    sh[tid] = fmaxf(acc, 0.f);
    __syncthreads();

    float p = 0.f;
    if (tid < 128) {
        p = b2[tid];
        for (int k = 0; k < 256; ++k) p = fmaf(sh[k], w2[k * 128 + tid], p);
        red[tid] = p * p;
    }
    __syncthreads();
    for (int s = 64; s > 0; s >>= 1) {
        if (tid < s) red[tid] += red[tid + s];
        __syncthreads();
    }
    if (tid < 128) {
        const float nrm = fmaxf(sqrtf(red[0]), 1e-12f);
        nproj[b * 128 + tid] = p / nrm;
    }
}

// one block per row i of the 64x64 sim matrix; log-softmax diag term
__global__ __launch_bounds__(256) void sim_k(
    const float* __restrict__ nproj, float* __restrict__ rowterm)
{
    __shared__ float ri[128];
    __shared__ float srow[64];
    const int i = blockIdx.x, t = threadIdx.x;
    if (t < 128) ri[t] = nproj[i * 128 + t];
    __syncthreads();

    const int j = t >> 2, q = t & 3;
    float d = 0.f;
    for (int k = q * 32; k < q * 32 + 32; ++k)
        d = fmaf(ri[k], nproj[j * 128 + k], d);
    d += __shfl_xor(d, 1);
    d += __shfl_xor(d, 2);
    if (q == 0) srow[j] = d * 10.f;   // / TEMP
    __syncthreads();

    if (t < 64) {
        float v = srow[t];
        float mx = v;
#pragma unroll
        for (int m = 1; m < 64; m <<= 1) mx = fmaxf(mx, __shfl_xor(mx, m));
        float e = expf(v - mx);
#pragma unroll
        for (int m = 1; m < 64; m <<= 1) e += __shfl_xor(e, m);
        if (t == 0) rowterm[i] = srow[i] - (mx + logf(e));
    }
}

__global__ __launch_bounds__(64) void final_k(
    const float* __restrict__ rowterm, const float* __restrict__ sums,
    float* __restrict__ out5)
{
    const int t = threadIdx.x;
    float c = rowterm[t];
#pragma unroll
    for (int m = 1; m < 64; m <<= 1) c += __shfl_xor(c, m);
    if (t == 0) {
        const float contr = -c / 64.f;
        const float recon = sums[0] / ((float)BT_TOK * (float)D_IN);
        const float commit = sums[1] / ((float)BT_TOK * (float)H2D);
        const float cbl = commit;
        const float total = recon * 1.0f + commit * 1.0f + cbl * 0.25f + contr * 0.5f;
        out5[0] = total;
        out5[1] = recon;
        out5[2] = commit;
        out5[3] = cbl;
        out5[4] = contr;
    }
}

extern "C" void kernel_launch(void* const* d_in, const int* in_sizes, int n_in,
                              void* d_out, int out_size, void* d_ws, size_t ws_size,
                              hipStream_t stream)
{
    const float* x       = (const float*)d_in[0];
    const float* enc_w1  = (const float*)d_in[1];
    const float* enc_b1  = (const float*)d_in[2];
    const float* ln1_g   = (const float*)d_in[3];
    const float* ln1_b   = (const float*)d_in[4];
    const float* enc_w2  = (const float*)d_in[5];
    const float* enc_b2  = (const float*)d_in[6];
    const float* ln2_g   = (const float*)d_in[7];
    const float* ln2_b   = (const float*)d_in[8];
    const float* codebook= (const float*)d_in[9];
    const float* dec_w1  = (const float*)d_in[10];
    const float* dec_b1  = (const float*)d_in[11];
    const float* dec_w2  = (const float*)d_in[12];
    const float* dec_b2  = (const float*)d_in[13];
    const float* proj_w1 = (const float*)d_in[14];
    const float* proj_b1 = (const float*)d_in[15];
    const float* proj_w2 = (const float*)d_in[16];
    const float* proj_b2 = (const float*)d_in[17];
    float* out = (float*)d_out;

    char* wsb = (char*)d_ws;
    size_t off = 0;
    auto alloc = [&](size_t bytes) {
        void* p = wsb + off;
        off += (bytes + 255) & ~(size_t)255;
        return p;
    };

    f16* h1h  = (f16*)alloc((size_t)BT_TOK * H1D * 2);
    f16* h1l  = (f16*)alloc((size_t)BT_TOK * H1D * 2);
    f16* ench = (f16*)alloc((size_t)BT_TOK * H2D * 2);
    f16* encl = (f16*)alloc((size_t)BT_TOK * H2D * 2);
    f16* w1h  = (f16*)alloc((size_t)H1D * D_IN * 2);
    f16* w1l  = (f16*)alloc((size_t)H1D * D_IN * 2);
    f16* w2h  = (f16*)alloc((size_t)H2D * H1D * 2);
    f16* w2l  = (f16*)alloc((size_t)H2D * H1D * 2);
    f16* cbh  = (f16*)alloc((size_t)KCB * H2D * 2);
    f16* cbl  = (f16*)alloc((size_t)KCB * H2D * 2);
    f16* dw1h = (f16*)alloc((size_t)H1D * H2D * 2);   // [768][512]
    f16* dw1l = (f16*)alloc((size_t)H1D * H2D * 2);
    f16* dw2h = (f16*)alloc((size_t)D_IN * H1D * 2);  // [1024][768]
    f16* dw2l = (f16*)alloc((size_t)D_IN * H1D * 2);
    f16* Uh   = (f16*)alloc((size_t)KCB * H1D * 2);   // relu(cb@W1+b1) pair
    f16* Ul   = (f16*)alloc((size_t)KCB * H1D * 2);
    float* Vf = (float*)alloc((size_t)KCB * D_IN * 4); // per-code decoded rows
    float* cnorm  = (float*)alloc(KCB * 4);
    float* enorm  = (float*)alloc(BT_TOK * 4);
    float* cand_v = (float*)alloc((size_t)BT_TOK * 8 * 4);
    int*   cand_i = (int*)alloc((size_t)BT_TOK * 8 * 4);
    int*   idxbuf = (int*)alloc(BT_TOK * 4);
    float* ppart  = (float*)alloc(64 * 8 * 512 * 4);
    float* nproj  = (float*)alloc(64 * 128 * 4);
    float* rowterm= (float*)alloc(64 * 4);
    float* sums   = (float*)alloc(2 * 4);

    const dim3 blk(256);
    const dim3 gblk(512);

    // prep: weight transpose-splits + codebook split + cnorm + sums
    prep_k<<<dim3(2561), blk, 0, stream>>>(
        enc_w1, w1h, w1l, enc_w2, w2h, w2l, codebook, cbh, cbl,
        dec_w1, dw1h, dw1l, dec_w2, dw2h, dw2l, cnorm, sums);

    // per-code decoder tables:
    // U = relu(cb @ dec_w1 + b1)  [512 x 768];  V = U @ dec_w2 + b2 [512 x 1024]
    sgemm_k<2, false><<<dim3(H1D / 128, KCB / 256), gblk, 0, stream>>>(
        nullptr, cbh, cbl, dw1h, dw1l, dec_b1, Uh, Ul, nullptr,
        nullptr, nullptr, nullptr, H1D, H2D);
    sgemm_k<3, false><<<dim3(D_IN / 128, KCB / 256), gblk, 0, stream>>>(
        nullptr, Uh, Ul, dw2h, dw2l, dec_b2, nullptr, nullptr, Vf,
        nullptr, nullptr, nullptr, D_IN, H1D);

    // encoder layer 1: h1 = x @ enc_w1 + b1 (fp32 A staged directly)
    sgemm_k<0, true><<<dim3(H1D / 128, BT_TOK / 256), gblk, 0, stream>>>(
        x, nullptr, nullptr, w1h, w1l, enc_b1, h1h, h1l, nullptr,
        nullptr, nullptr, nullptr, H1D, D_IN);
    ln_pair_k<H1D, false><<<dim3(BT_TOK / 4), blk, 0, stream>>>(h1h, h1l, ln1_g, ln1_b, nullptr);

    // encoder layer 2: enc = h1 @ enc_w2 + b2
    sgemm_k<0, false><<<dim3(H2D / 128, BT_TOK / 256), gblk, 0, stream>>>(
        nullptr, h1h, h1l, w2h, w2l, enc_b2, ench, encl, nullptr,
        nullptr, nullptr, nullptr, H2D, H1D);
    ln_pair_k<H2D, true><<<dim3(BT_TOK / 4), blk, 0, stream>>>(ench, encl, ln2_g, ln2_b, enorm);

    // VQ scores + tile argmin
    sgemm_k<1, false><<<dim3(KCB / 128, BT_TOK / 256), gblk, 0, stream>>>(
        nullptr, ench, encl, cbh, cbl, nullptr, nullptr, nullptr, nullptr,
        cnorm, cand_v, cand_i, KCB, H2D);

    // merged argmin-finalize + commit + recon
    vqrr_k<<<dim3(BT_TOK / 128), blk, 0, stream>>>(
        cand_v, cand_i, enorm, out, idxbuf, sums, Vf, x);

    pooled_part_k<<<dim3(64, 8), blk, 0, stream>>>(idxbuf, codebook, ppart);
    proj_k<<<dim3(64), blk, 0, stream>>>(ppart, proj_w1, proj_b1, proj_w2, proj_b2, nproj);
    sim_k<<<dim3(64), blk, 0, stream>>>(nproj, rowterm);
    final_k<<<dim3(1), dim3(64), 0, stream>>>(rowterm, sums, out + BT_TOK);
}

// Round 5
// 731.639 us; speedup vs baseline: 1.0961x; 1.0101x over previous
//
#include <hip/hip_runtime.h>
#include <math.h>

#define BT_TOK 32768
#define D_IN   1024
#define H1D    768
#define H2D    512
#define KCB    512

typedef _Float16 f16;
typedef _Float16 half8v __attribute__((ext_vector_type(8)));
typedef float f32x4 __attribute__((ext_vector_type(4)));

#define GLDS16(g, l) \
    __builtin_amdgcn_global_load_lds((const __attribute__((address_space(1))) void*)(g), \
                                     (__attribute__((address_space(3))) void*)(l), 16, 0, 0)

// split convention: hi = f16(v), lo = f16((v-hi)*2048); v ~= hi + lo/2048
__device__ __forceinline__ void splitf(float v, f16& h, f16& l) {
    h = (f16)v;
    l = (f16)((v - (float)h) * 2048.f);
}

// ---------------------------------------------------------------------------
// Split-FP16 MFMA GEMM, 4-phase fine-interleaved schedule (m196/m201 port):
//   BM=256 x BN=128, BK=32, 512 thr = 8 waves (4M x 2N), per-wave 64x64.
//   LDS: TRIPLE-buffered, 144 KiB. Per K-tile, 4 phases (phase p = ni p):
//   {ds_read B[p] pair (+all A in P0) | issue 2/2/1/1 GLDS of tile t+2 ->
//    s_barrier -> lgkmcnt(0)+sched_barrier -> setprio(1) 12 MFMA setprio(0)
//    -> [P3: counted vmcnt(6), never 0 mid-loop] -> s_barrier}.
//   This is the {fine-spread issue + counted wait} cell of the experiment
//   matrix (R2={coarse,drain}, R3={coarse,counted} were null; m196 says the
//   per-phase ds_read||GLDS||MFMA interleave is the lever).
// AF32 (GEMM1): A fp32 staged raw, split to f16 pair in-register in P0.
// EPI 0: +bias -> f16 pair. 1: VQ tile-argmin. 2: +bias,relu -> f16 pair.
// EPI 3: +bias -> fp32.
// ---------------------------------------------------------------------------
template<int EPI, bool AF32>
__global__ __launch_bounds__(512, 2) void sgemm_k(
    const float* __restrict__ Af,
    const f16* __restrict__ Ah, const f16* __restrict__ Al,
    const f16* __restrict__ Bh, const f16* __restrict__ Bl,
    const float* __restrict__ bias,
    f16* __restrict__ Ch, f16* __restrict__ Cl,
    float* __restrict__ Cf,
    const float* __restrict__ cnorm,
    float* __restrict__ cand_v, int* __restrict__ cand_i,
    int N, int Kd)
{
    // AF32: sAf 3x32K [0,96K)              | sBh 3x8K [96K,120K) | sBl 3x8K [120K,144K)
    // f16 : sAh 3x16K [0,48K), sAl [48,96K)| same B region
    __shared__ __align__(16) char lds[147456];
    char* const ldsb = lds;
    constexpr int BBASE = 98304;

    const int t = threadIdx.x;
    const int lane = t & 63, wave = t >> 6;
    const int wm = wave & 3, wn = wave >> 2;

    const int nwg = gridDim.x * gridDim.y;
    int flat = blockIdx.y * gridDim.x + blockIdx.x;
    if ((nwg & 7) == 0) flat = (flat & 7) * (nwg >> 3) + (flat >> 3);
    const int bx = flat % gridDim.x;
    const int by = flat / gridDim.x;
    const int row0 = by * 256, col0 = bx * 128;

    f32x4 acc_h[4][4], acc_l[4][4];
#pragma unroll
    for (int i = 0; i < 4; ++i)
#pragma unroll
        for (int j = 0; j < 4; ++j) {
            acc_h[i][j] = (f32x4){0.f, 0.f, 0.f, 0.f};
            acc_l[i][j] = (f32x4){0.f, 0.f, 0.f, 0.f};
        }

    // staging addressing
    const int srow = t >> 2;
    const int scol = ((t & 3) ^ ((t >> 3) & 3)) * 8;
    const f16* gBh = Bh + (size_t)(col0 + srow) * Kd + scol;
    const f16* gBl = Bl + (size_t)(col0 + srow) * Kd + scol;
    const float* gAf = AF32 ?
        (Af + (size_t)(row0 + (t >> 3)) * Kd + (((t & 7) ^ ((t >> 3) & 7)) << 2)) : nullptr;
    const f16* gAh = AF32 ? nullptr : (Ah + (size_t)(row0 + srow) * Kd + scol);
    const f16* gAl = AF32 ? nullptr : (Al + (size_t)(row0 + srow) * Kd + scol);
    const size_t rskip = (size_t)128 * Kd;

    // fragment read addressing
    const int fr = lane & 15;
    const int c0 = lane >> 4;
    const int fko = ((c0 ^ ((lane >> 1) & 3)) << 4);
    const int auo = fr * 64 + fko;
    const int abase16 = wm * 4096 + auo;
    const int bbase = wn * 4096 + auo;
    const int fr7 = lane & 7;
    const int offA1 = (((2 * c0) ^ fr7) << 4);
    const int offA2 = (((2 * c0 + 1) ^ fr7) << 4);
    const int abase32 = (wm * 64 + fr) * 128;
    const int aBufSz = AF32 ? 32768 : 16384;

    // GLDS pieces g0..g5 for tile at k-offset ko into buffer sb
#define G_B0(sb, ko) GLDS16(gBh + (ko), ldsb + BBASE + (sb) * 8192 + t * 16)
#define G_B1(sb, ko) GLDS16(gBl + (ko), ldsb + BBASE + (sb) * 8192 + t * 16 + 24576)
#define G_A0(sb, ko) do { if (AF32) GLDS16(gAf + (ko), ldsb + (sb) * 32768 + t * 16); \
                          else GLDS16(gAh + (ko), ldsb + (sb) * 16384 + t * 16); } while (0)
#define G_A1(sb, ko) do { if (AF32) GLDS16(gAf + (ko) + (size_t)64 * Kd, ldsb + (sb) * 32768 + t * 16 + 8192); \
                          else GLDS16(gAh + (ko) + rskip, ldsb + (sb) * 16384 + t * 16 + 8192); } while (0)
#define G_A2(sb, ko) do { if (AF32) GLDS16(gAf + (ko) + (size_t)128 * Kd, ldsb + (sb) * 32768 + t * 16 + 16384); \
                          else GLDS16(gAl + (ko), ldsb + (sb) * 16384 + t * 16 + 49152); } while (0)
#define G_A3(sb, ko) do { if (AF32) GLDS16(gAf + (ko) + (size_t)192 * Kd, ldsb + (sb) * 32768 + t * 16 + 24576); \
                          else GLDS16(gAl + (ko) + rskip, ldsb + (sb) * 16384 + t * 16 + 49152 + 8192); } while (0)
#define G_ALL(sb, ko) do { G_B0(sb, ko); G_B1(sb, ko); G_A0(sb, ko); G_A1(sb, ko); G_A2(sb, ko); G_A3(sb, ko); } while (0)

    // prologue: stage tiles 0,1 fully; wait for tile 0 (6 newest = tile 1 fly)
    G_ALL(0, 0);
    G_ALL(1, 32);
    asm volatile("s_waitcnt vmcnt(6)" ::: "memory");
    __builtin_amdgcn_s_barrier();

    int cur = 0, sbuf = 2;
    for (int k0 = 0; k0 < Kd; k0 += 32) {
        const bool has2 = (k0 + 64 < Kd);
        const bool has1 = (k0 + 32 < Kd);
        const int kn = k0 + 64;
        const char* pa = ldsb + cur * aBufSz;
        const char* pb = ldsb + BBASE + cur * 8192 + bbase;

        half8v fah[4], fal[4];
        half8v fbh, fbl;

        // ================= phase 0: all A + B0; issue g0,g1 =================
        {
            f32x4 ra[4], rb[4];
            if (AF32) {
#pragma unroll
                for (int mi = 0; mi < 4; ++mi) {
                    ra[mi] = *(const f32x4*)(pa + abase32 + mi * 2048 + offA1);
                    rb[mi] = *(const f32x4*)(pa + abase32 + mi * 2048 + offA2);
                }
            } else {
#pragma unroll
                for (int mi = 0; mi < 4; ++mi) {
                    fah[mi] = *(const half8v*)(pa + abase16 + mi * 1024);
                    fal[mi] = *(const half8v*)(pa + 49152 + abase16 + mi * 1024);
                }
            }
            fbh = *(const half8v*)(pb);
            fbl = *(const half8v*)(pb + 24576);
            if (has2) { G_B0(sbuf, kn); G_B1(sbuf, kn); }
            __builtin_amdgcn_s_barrier();
            asm volatile("s_waitcnt lgkmcnt(0)" ::: "memory");
            __builtin_amdgcn_sched_barrier(0);
            if (AF32) {
#pragma unroll
                for (int mi = 0; mi < 4; ++mi)
#pragma unroll
                    for (int j = 0; j < 4; ++j) {
                        f16 h, l;
                        splitf(ra[mi][j], h, l); fah[mi][j] = h; fal[mi][j] = l;
                        splitf(rb[mi][j], h, l); fah[mi][j + 4] = h; fal[mi][j + 4] = l;
                    }
            }
            __builtin_amdgcn_s_setprio(1);
#pragma unroll
            for (int mi = 0; mi < 4; ++mi) {
                acc_h[mi][0] = __builtin_amdgcn_mfma_f32_16x16x32_f16(fah[mi], fbh, acc_h[mi][0], 0, 0, 0);
                acc_l[mi][0] = __builtin_amdgcn_mfma_f32_16x16x32_f16(fah[mi], fbl, acc_l[mi][0], 0, 0, 0);
                acc_l[mi][0] = __builtin_amdgcn_mfma_f32_16x16x32_f16(fal[mi], fbh, acc_l[mi][0], 0, 0, 0);
            }
            __builtin_amdgcn_s_setprio(0);
            __builtin_amdgcn_s_barrier();
        }

        // ================= phase 1: B1; issue g2,g3 =================
        {
            fbh = *(const half8v*)(pb + 1024);
            fbl = *(const half8v*)(pb + 24576 + 1024);
            if (has2) { G_A0(sbuf, kn); G_A1(sbuf, kn); }
            __builtin_amdgcn_s_barrier();
            asm volatile("s_waitcnt lgkmcnt(0)" ::: "memory");
            __builtin_amdgcn_sched_barrier(0);
            __builtin_amdgcn_s_setprio(1);
#pragma unroll
            for (int mi = 0; mi < 4; ++mi) {
                acc_h[mi][1] = __builtin_amdgcn_mfma_f32_16x16x32_f16(fah[mi], fbh, acc_h[mi][1], 0, 0, 0);
                acc_l[mi][1] = __builtin_amdgcn_mfma_f32_16x16x32_f16(fah[mi], fbl, acc_l[mi][1], 0, 0, 0);
                acc_l[mi][1] = __builtin_amdgcn_mfma_f32_16x16x32_f16(fal[mi], fbh, acc_l[mi][1], 0, 0, 0);
            }
            __builtin_amdgcn_s_setprio(0);
            __builtin_amdgcn_s_barrier();
        }

        // ================= phase 2: B2; issue g4 =================
        {
            fbh = *(const half8v*)(pb + 2048);
            fbl = *(const half8v*)(pb + 24576 + 2048);
            if (has2) { G_A2(sbuf, kn); }
            __builtin_amdgcn_s_barrier();
            asm volatile("s_waitcnt lgkmcnt(0)" ::: "memory");
            __builtin_amdgcn_sched_barrier(0);
            __builtin_amdgcn_s_setprio(1);
#pragma unroll
            for (int mi = 0; mi < 4; ++mi) {
                acc_h[mi][2] = __builtin_amdgcn_mfma_f32_16x16x32_f16(fah[mi], fbh, acc_h[mi][2], 0, 0, 0);
                acc_l[mi][2] = __builtin_amdgcn_mfma_f32_16x16x32_f16(fah[mi], fbl, acc_l[mi][2], 0, 0, 0);
                acc_l[mi][2] = __builtin_amdgcn_mfma_f32_16x16x32_f16(fal[mi], fbh, acc_l[mi][2], 0, 0, 0);
            }
            __builtin_amdgcn_s_setprio(0);
            __builtin_amdgcn_s_barrier();
        }

        // ================= phase 3: B3; issue g5; counted wait =================
        {
            fbh = *(const half8v*)(pb + 3072);
            fbl = *(const half8v*)(pb + 24576 + 3072);
            if (has2) { G_A3(sbuf, kn); }
            __builtin_amdgcn_s_barrier();
            asm volatile("s_waitcnt lgkmcnt(0)" ::: "memory");
            __builtin_amdgcn_sched_barrier(0);
            __builtin_amdgcn_s_setprio(1);
#pragma unroll
            for (int mi = 0; mi < 4; ++mi) {
                acc_h[mi][3] = __builtin_amdgcn_mfma_f32_16x16x32_f16(fah[mi], fbh, acc_h[mi][3], 0, 0, 0);
                acc_l[mi][3] = __builtin_amdgcn_mfma_f32_16x16x32_f16(fah[mi], fbl, acc_l[mi][3], 0, 0, 0);
                acc_l[mi][3] = __builtin_amdgcn_mfma_f32_16x16x32_f16(fal[mi], fbh, acc_l[mi][3], 0, 0, 0);
            }
            __builtin_amdgcn_s_setprio(0);
            // counted wait: tile t+1 landed; t+2's 6 loads stay in flight (T4)
            if (has2)      asm volatile("s_waitcnt vmcnt(6)" ::: "memory");
            else if (has1) asm volatile("s_waitcnt vmcnt(0)" ::: "memory");
            __builtin_amdgcn_s_barrier();
        }

        cur = (cur == 2) ? 0 : cur + 1;
        sbuf = (sbuf == 2) ? 0 : sbuf + 1;
    }
#undef G_ALL
#undef G_A3
#undef G_A2
#undef G_A1
#undef G_A0
#undef G_B1
#undef G_B0

    const int cR = (lane >> 4) * 4;   // C/D: row = quad*4 + reg, col = lane&15
    const int cC = lane & 15;

    if (EPI == 0 || EPI == 2 || EPI == 3) {
#pragma unroll
        for (int ni = 0; ni < 4; ++ni) {
            const int col = col0 + wn * 64 + ni * 16 + cC;
            const float bb = bias[col];
#pragma unroll
            for (int mi = 0; mi < 4; ++mi)
#pragma unroll
                for (int r = 0; r < 4; ++r) {
                    const size_t row = row0 + wm * 64 + mi * 16 + cR + r;
                    float v = acc_h[mi][ni][r] + acc_l[mi][ni][r] * (1.f / 2048.f) + bb;
                    if (EPI == 2) v = fmaxf(v, 0.f);
                    if (EPI == 3) {
                        Cf[row * N + col] = v;
                    } else {
                        f16 vh, vl;
                        splitf(v, vh, vl);
                        Ch[row * N + col] = vh;
                        Cl[row * N + col] = vl;
                    }
                }
        }
    } else {  // EPI == 1: VQ tile argmin
#pragma unroll
        for (int mi = 0; mi < 4; ++mi)
#pragma unroll
            for (int r = 0; r < 4; ++r) {
                float bestv = 1e30f;
                int besti = 0;
#pragma unroll
                for (int ni = 0; ni < 4; ++ni) {
                    const int col = col0 + wn * 64 + ni * 16 + cC;
                    const float v = cnorm[col]
                        - 2.f * (acc_h[mi][ni][r] + acc_l[mi][ni][r] * (1.f / 2048.f));
                    if (v < bestv || (v == bestv && col < besti)) { bestv = v; besti = col; }
                }
#pragma unroll
                for (int m = 1; m < 16; m <<= 1) {
                    const float ov = __shfl_xor(bestv, m);
                    const int oi = __shfl_xor(besti, m);
                    if (ov < bestv || (ov == bestv && oi < besti)) { bestv = ov; besti = oi; }
                }
                if (cC == 0) {
                    const size_t row = row0 + wm * 64 + mi * 16 + cR + r;
                    cand_v[row * 8 + bx * 2 + wn] = bestv;
                    cand_i[row * 8 + bx * 2 + wn] = besti;
                }
            }
    }
}

// ---------------------------------------------------------------------------
// Fused prep: coalesced 32x32 LDS-tile transpose-splits for all 4 weights,
// vectorized codebook split, codebook row norms, sums init.
// ---------------------------------------------------------------------------
__global__ __launch_bounds__(256) void prep_k(
    const float* __restrict__ enc_w1, f16* __restrict__ w1h, f16* __restrict__ w1l,
    const float* __restrict__ enc_w2, f16* __restrict__ w2h, f16* __restrict__ w2l,
    const float* __restrict__ codebook, f16* __restrict__ cbh, f16* __restrict__ cbl,
    const float* __restrict__ dec_w1, f16* __restrict__ dw1h, f16* __restrict__ dw1l,
    const float* __restrict__ dec_w2, f16* __restrict__ dw2h, f16* __restrict__ dw2l,
    float* __restrict__ cnorm, float* __restrict__ sums)
{
    __shared__ float tile[32][33];
    const int b = blockIdx.x;
    const int t = threadIdx.x;
    if (b < 2304) {
        const float* W; f16* Oh; f16* Ol; int K, N, tb;
        if (b < 768)       { W = enc_w1; Oh = w1h;  Ol = w1l;  K = 1024; N = 768;  tb = b; }
        else if (b < 1152) { W = enc_w2; Oh = w2h;  Ol = w2l;  K = 768;  N = 512;  tb = b - 768; }
        else if (b < 1536) { W = dec_w1; Oh = dw1h; Ol = dw1l; K = 512;  N = 768;  tb = b - 1152; }
        else               { W = dec_w2; Oh = dw2h; Ol = dw2l; K = 768;  N = 1024; tb = b - 1536; }
        const int ntx = N >> 5;
        const int tk = tb / ntx, tn = tb - tk * ntx;
        const int k0 = tk << 5, n0 = tn << 5;
        const int tx = t & 31, ty = t >> 5;
#pragma unroll
        for (int p = 0; p < 4; ++p)
            tile[ty + p * 8][tx] = W[(size_t)(k0 + ty + p * 8) * N + n0 + tx];
        __syncthreads();
#pragma unroll
        for (int p = 0; p < 4; ++p) {
            const int row = ty + p * 8;
            f16 h, l; splitf(tile[tx][row], h, l);
            Oh[(size_t)(n0 + row) * K + k0 + tx] = h;
            Ol[(size_t)(n0 + row) * K + k0 + tx] = l;
        }
    } else if (b < 2432) {                // codebook split, vectorized (512x512)
        const size_t i = ((size_t)(b - 2304) * 256 + t) * 8;
        const float4 f0 = *(const float4*)(codebook + i);
        const float4 f1 = *(const float4*)(codebook + i + 4);
        const float fv[8] = {f0.x, f0.y, f0.z, f0.w, f1.x, f1.y, f1.z, f1.w};
        f16 hv[8] __attribute__((aligned(16)));
        f16 lv[8] __attribute__((aligned(16)));
#pragma unroll
        for (int j = 0; j < 8; ++j) splitf(fv[j], hv[j], lv[j]);
        *(half8v*)(cbh + i) = *(half8v*)hv;
        *(half8v*)(cbl + i) = *(half8v*)lv;
    } else if (b < 2560) {                // codebook row sum-squares
        const int lane = t & 63, wid = t >> 6;
        const size_t row = (size_t)(b - 2432) * 4 + wid;
        const float* p = codebook + row * 512;
        float s = 0.f;
#pragma unroll
        for (int e = 0; e < 8; ++e) { const float v = p[lane + e * 64]; s = fmaf(v, v, s); }
#pragma unroll
        for (int m = 1; m < 64; m <<= 1) s += __shfl_xor(s, m);
        if (lane == 0) cnorm[row] = s;
    } else {                              // init loss accumulators
        if (t < 2) sums[t] = 0.f;
    }
}

// ---------------------------------------------------------------------------
// LayerNorm + ReLU on f16 hi/lo pair (in place), fp32 math, vectorized.
// ---------------------------------------------------------------------------
template<int H, bool ENORM>
__global__ __launch_bounds__(256) void ln_pair_k(
    f16* __restrict__ hi, f16* __restrict__ lo, const float* __restrict__ g,
    const float* __restrict__ b, float* __restrict__ enorm)
{
    constexpr int NCH = H / 8;
    constexpr int MAXC = (NCH + 63) / 64;
    const int lane = threadIdx.x & 63;
    const int wid = threadIdx.x >> 6;
    const size_t row = (size_t)blockIdx.x * 4 + wid;
    f16* ph = hi + row * H;
    f16* pl = lo + row * H;

    float h[MAXC * 8];
    float s = 0.f;
#pragma unroll
    for (int e = 0; e < MAXC; ++e) {
        const int c = lane + e * 64;
        if ((NCH % 64 == 0) || c < NCH) {
            const half8v vh = *(const half8v*)(ph + c * 8);
            const half8v vl = *(const half8v*)(pl + c * 8);
#pragma unroll
            for (int j = 0; j < 8; ++j) {
                h[e * 8 + j] = (float)vh[j] + (float)vl[j] * (1.f / 2048.f);
                s += h[e * 8 + j];
            }
        }
    }
#pragma unroll
    for (int m = 1; m < 64; m <<= 1) s += __shfl_xor(s, m);
    const float mu = s * (1.f / H);

    float vs = 0.f;
#pragma unroll
    for (int e = 0; e < MAXC; ++e) {
        const int c = lane + e * 64;
        if ((NCH % 64 == 0) || c < NCH) {
#pragma unroll
            for (int j = 0; j < 8; ++j) {
                const float d = h[e * 8 + j] - mu;
                vs = fmaf(d, d, vs);
            }
        }
    }
#pragma unroll
    for (int m = 1; m < 64; m <<= 1) vs += __shfl_xor(vs, m);
    const float rstd = rsqrtf(vs * (1.f / H) + 1e-5f);

    float q = 0.f;
#pragma unroll
    for (int e = 0; e < MAXC; ++e) {
        const int c = lane + e * 64;
        if ((NCH % 64 == 0) || c < NCH) {
            f16 oh[8] __attribute__((aligned(16)));
            f16 ol[8] __attribute__((aligned(16)));
#pragma unroll
            for (int j = 0; j < 8; ++j) {
                float o = (h[e * 8 + j] - mu) * rstd * g[c * 8 + j] + b[c * 8 + j];
                o = fmaxf(o, 0.f);
                splitf(o, oh[j], ol[j]);
                q = fmaf(o, o, q);
            }
            *(half8v*)(ph + c * 8) = *(half8v*)oh;
            *(half8v*)(pl + c * 8) = *(half8v*)ol;
        }
    }
    if (ENORM) {
#pragma unroll
        for (int m = 1; m < 64; m <<= 1) q += __shfl_xor(q, m);
        if (lane == 0) enorm[row] = q;
    }
}

// ---------------------------------------------------------------------------
// Merged VQ-reduce + recon: 256 blocks x 128 tokens.
// ---------------------------------------------------------------------------
__global__ __launch_bounds__(256) void vqrr_k(
    const float* __restrict__ cand_v, const int* __restrict__ cand_i,
    const float* __restrict__ enorm, float* __restrict__ out_idx_f,
    int* __restrict__ out_idx, float* __restrict__ sums,
    const float* __restrict__ V, const float* __restrict__ x)
{
    __shared__ int sidx[128];
    __shared__ float red[256];
    const int tid = threadIdx.x;
    const int blk = blockIdx.x;

    float commit = 0.f;
    if (tid < 128) {
        const int m = blk * 128 + tid;
        float bv = cand_v[(size_t)m * 8];
        int bi = cand_i[(size_t)m * 8];
#pragma unroll
        for (int tt = 1; tt < 8; ++tt) {
            const float v = cand_v[(size_t)m * 8 + tt];
            const int i = cand_i[(size_t)m * 8 + tt];
            if (v < bv || (v == bv && i < bi)) { bv = v; bi = i; }
        }
        out_idx_f[m] = (float)bi;
        out_idx[m] = bi;
        sidx[tid] = bi;
        commit = enorm[m] + bv;
    }
    red[tid] = (tid < 128) ? commit : 0.f;
    __syncthreads();
    for (int s = 128; s > 0; s >>= 1) {
        if (tid < s) red[tid] += red[tid + s];
        __syncthreads();
    }
    if (tid == 0) atomicAdd(sums + 1, red[0]);
    __syncthreads();

    float ls = 0.f;
    for (int tt = 0; tt < 128; ++tt) {
        const int id = sidx[tt];
        const float4 v4 = ((const float4*)(V + (size_t)id * D_IN))[tid];
        const float4 x4 = ((const float4*)(x + (size_t)(blk * 128 + tt) * D_IN))[tid];
        const float d0 = v4.x - x4.x, d1 = v4.y - x4.y;
        const float d2 = v4.z - x4.z, d3 = v4.w - x4.w;
        ls = fmaf(d0, d0, ls); ls = fmaf(d1, d1, ls);
        ls = fmaf(d2, d2, ls); ls = fmaf(d3, d3, ls);
    }
    __syncthreads();
    red[tid] = ls;
    __syncthreads();
    for (int s = 128; s > 0; s >>= 1) {
        if (tid < s) red[tid] += red[tid + s];
        __syncthreads();
    }
    if (tid == 0) atomicAdd(sums, red[0]);
}

// pooled mean of codebook rows: two-stage for parallelism
__global__ __launch_bounds__(256) void pooled_part_k(
    const int* __restrict__ idx, const float* __restrict__ cb,
    float* __restrict__ part)
{
    const int b = blockIdx.x, c = blockIdx.y;   // grid (64, 8)
    const int d = threadIdx.x;
    float a0 = 0.f, a1 = 0.f;
    for (int t = c * 64; t < c * 64 + 64; ++t) {
        const int id = idx[b * 512 + t];
        a0 += cb[(size_t)id * 512 + d];
        a1 += cb[(size_t)id * 512 + d + 256];
    }
    part[((b * 8 + c) * 512) + d] = a0;
    part[((b * 8 + c) * 512) + d + 256] = a1;
}

// proj (reads ppart directly, folds pooled_fin)
__global__ __launch_bounds__(256) void proj_k(
    const float* __restrict__ part, const float* __restrict__ w1,
    const float* __restrict__ b1, const float* __restrict__ w2,
    const float* __restrict__ b2, float* __restrict__ nproj)
{
    __shared__ float sp[512];
    __shared__ float sh[256];
    __shared__ float red[128];
    const int b = blockIdx.x, tid = threadIdx.x;
    {
        float a0 = 0.f, a1 = 0.f;
#pragma unroll
        for (int c = 0; c < 8; ++c) {
            a0 += part[((b * 8 + c) * 512) + tid];
            a1 += part[((b * 8 + c) * 512) + tid + 256];
        }
        sp[tid] = a0 * (1.f / 512.f);
        sp[tid + 256] = a1 * (1.f / 512.f);
    }
    __syncthreads();

    float acc = b1[tid];
    for (int k = 0; k < 512; ++k) acc = fmaf(sp[k], w1[k * 256 + tid], acc);
    sh[tid] = fmaxf(acc, 0.f);
    __syncthreads();

    float p = 0.f;
    if (tid < 128) {
        p = b2[tid];
        for (int k = 0; k < 256; ++k) p = fmaf(sh[k], w2[k * 128 + tid], p);
        red[tid] = p * p;
    }
    __syncthreads();
    for (int s = 64; s > 0; s >>= 1) {
        if (tid < s) red[tid] += red[tid + s];
        __syncthreads();
    }
    if (tid < 128) {
        const float nrm = fmaxf(sqrtf(red[0]), 1e-12f);
        nproj[b * 128 + tid] = p / nrm;
    }
}

// one block per row i of the 64x64 sim matrix; log-softmax diag term
__global__ __launch_bounds__(256) void sim_k(
    const float* __restrict__ nproj, float* __restrict__ rowterm)
{
    __shared__ float ri[128];
    __shared__ float srow[64];
    const int i = blockIdx.x, t = threadIdx.x;
    if (t < 128) ri[t] = nproj[i * 128 + t];
    __syncthreads();

    const int j = t >> 2, q = t & 3;
    float d = 0.f;
    for (int k = q * 32; k < q * 32 + 32; ++k)
        d = fmaf(ri[k], nproj[j * 128 + k], d);
    d += __shfl_xor(d, 1);
    d += __shfl_xor(d, 2);
    if (q == 0) srow[j] = d * 10.f;   // / TEMP
    __syncthreads();

    if (t < 64) {
        float v = srow[t];
        float mx = v;
#pragma unroll
        for (int m = 1; m < 64; m <<= 1) mx = fmaxf(mx, __shfl_xor(mx, m));
        float e = expf(v - mx);
#pragma unroll
        for (int m = 1; m < 64; m <<= 1) e += __shfl_xor(e, m);
        if (t == 0) rowterm[i] = srow[i] - (mx + logf(e));
    }
}

__global__ __launch_bounds__(64) void final_k(
    const float* __restrict__ rowterm, const float* __restrict__ sums,
    float* __restrict__ out5)
{
    const int t = threadIdx.x;
    float c = rowterm[t];
#pragma unroll
    for (int m = 1; m < 64; m <<= 1) c += __shfl_xor(c, m);
    if (t == 0) {
        const float contr = -c / 64.f;
        const float recon = sums[0] / ((float)BT_TOK * (float)D_IN);
        const float commit = sums[1] / ((float)BT_TOK * (float)H2D);
        const float cbl = commit;
        const float total = recon * 1.0f + commit * 1.0f + cbl * 0.25f + contr * 0.5f;
        out5[0] = total;
        out5[1] = recon;
        out5[2] = commit;
        out5[3] = cbl;
        out5[4] = contr;
    }
}

extern "C" void kernel_launch(void* const* d_in, const int* in_sizes, int n_in,
                              void* d_out, int out_size, void* d_ws, size_t ws_size,
                              hipStream_t stream)
{
    const float* x       = (const float*)d_in[0];
    const float* enc_w1  = (const float*)d_in[1];
    const float* enc_b1  = (const float*)d_in[2];
    const float* ln1_g   = (const float*)d_in[3];
    const float* ln1_b   = (const float*)d_in[4];
    const float* enc_w2  = (const float*)d_in[5];
    const float* enc_b2  = (const float*)d_in[6];
    const float* ln2_g   = (const float*)d_in[7];
    const float* ln2_b   = (const float*)d_in[8];
    const float* codebook= (const float*)d_in[9];
    const float* dec_w1  = (const float*)d_in[10];
    const float* dec_b1  = (const float*)d_in[11];
    const float* dec_w2  = (const float*)d_in[12];
    const float* dec_b2  = (const float*)d_in[13];
    const float* proj_w1 = (const float*)d_in[14];
    const float* proj_b1 = (const float*)d_in[15];
    const float* proj_w2 = (const float*)d_in[16];
    const float* proj_b2 = (const float*)d_in[17];
    float* out = (float*)d_out;

    char* wsb = (char*)d_ws;
    size_t off = 0;
    auto alloc = [&](size_t bytes) {
        void* p = wsb + off;
        off += (bytes + 255) & ~(size_t)255;
        return p;
    };

    f16* h1h  = (f16*)alloc((size_t)BT_TOK * H1D * 2);
    f16* h1l  = (f16*)alloc((size_t)BT_TOK * H1D * 2);
    f16* ench = (f16*)alloc((size_t)BT_TOK * H2D * 2);
    f16* encl = (f16*)alloc((size_t)BT_TOK * H2D * 2);
    f16* w1h  = (f16*)alloc((size_t)H1D * D_IN * 2);
    f16* w1l  = (f16*)alloc((size_t)H1D * D_IN * 2);
    f16* w2h  = (f16*)alloc((size_t)H2D * H1D * 2);
    f16* w2l  = (f16*)alloc((size_t)H2D * H1D * 2);
    f16* cbh  = (f16*)alloc((size_t)KCB * H2D * 2);
    f16* cbl  = (f16*)alloc((size_t)KCB * H2D * 2);
    f16* dw1h = (f16*)alloc((size_t)H1D * H2D * 2);
    f16* dw1l = (f16*)alloc((size_t)H1D * H2D * 2);
    f16* dw2h = (f16*)alloc((size_t)D_IN * H1D * 2);
    f16* dw2l = (f16*)alloc((size_t)D_IN * H1D * 2);
    f16* Uh   = (f16*)alloc((size_t)KCB * H1D * 2);
    f16* Ul   = (f16*)alloc((size_t)KCB * H1D * 2);
    float* Vf = (float*)alloc((size_t)KCB * D_IN * 4);
    float* cnorm  = (float*)alloc(KCB * 4);
    float* enorm  = (float*)alloc(BT_TOK * 4);
    float* cand_v = (float*)alloc((size_t)BT_TOK * 8 * 4);
    int*   cand_i = (int*)alloc((size_t)BT_TOK * 8 * 4);
    int*   idxbuf = (int*)alloc(BT_TOK * 4);
    float* ppart  = (float*)alloc(64 * 8 * 512 * 4);
    float* nproj  = (float*)alloc(64 * 128 * 4);
    float* rowterm= (float*)alloc(64 * 4);
    float* sums   = (float*)alloc(2 * 4);

    const dim3 blk(256);
    const dim3 gblk(512);

    prep_k<<<dim3(2561), blk, 0, stream>>>(
        enc_w1, w1h, w1l, enc_w2, w2h, w2l, codebook, cbh, cbl,
        dec_w1, dw1h, dw1l, dec_w2, dw2h, dw2l, cnorm, sums);

    // per-code decoder tables
    sgemm_k<2, false><<<dim3(H1D / 128, KCB / 256), gblk, 0, stream>>>(
        nullptr, cbh, cbl, dw1h, dw1l, dec_b1, Uh, Ul, nullptr,
        nullptr, nullptr, nullptr, H1D, H2D);
    sgemm_k<3, false><<<dim3(D_IN / 128, KCB / 256), gblk, 0, stream>>>(
        nullptr, Uh, Ul, dw2h, dw2l, dec_b2, nullptr, nullptr, Vf,
        nullptr, nullptr, nullptr, D_IN, H1D);

    // encoder layer 1 (fp32 A staged directly)
    sgemm_k<0, true><<<dim3(H1D / 128, BT_TOK / 256), gblk, 0, stream>>>(
        x, nullptr, nullptr, w1h, w1l, enc_b1, h1h, h1l, nullptr,
        nullptr, nullptr, nullptr, H1D, D_IN);
    ln_pair_k<H1D, false><<<dim3(BT_TOK / 4), blk, 0, stream>>>(h1h, h1l, ln1_g, ln1_b, nullptr);

    // encoder layer 2
    sgemm_k<0, false><<<dim3(H2D / 128, BT_TOK / 256), gblk, 0, stream>>>(
        nullptr, h1h, h1l, w2h, w2l, enc_b2, ench, encl, nullptr,
        nullptr, nullptr, nullptr, H2D, H1D);
    ln_pair_k<H2D, true><<<dim3(BT_TOK / 4), blk, 0, stream>>>(ench, encl, ln2_g, ln2_b, enorm);

    // VQ scores + tile argmin
    sgemm_k<1, false><<<dim3(KCB / 128, BT_TOK / 256), gblk, 0, stream>>>(
        nullptr, ench, encl, cbh, cbl, nullptr, nullptr, nullptr, nullptr,
        cnorm, cand_v, cand_i, KCB, H2D);

    vqrr_k<<<dim3(BT_TOK / 128), blk, 0, stream>>>(
        cand_v, cand_i, enorm, out, idxbuf, sums, Vf, x);

    pooled_part_k<<<dim3(64, 8), blk, 0, stream>>>(idxbuf, codebook, ppart);
    proj_k<<<dim3(64), blk, 0, stream>>>(ppart, proj_w1, proj_b1, proj_w2, proj_b2, nproj);
    sim_k<<<dim3(64), blk, 0, stream>>>(nproj, rowterm);
    final_k<<<dim3(1), dim3(64), 0, stream>>>(rowterm, sums, out + BT_TOK);
}

// Round 6
// 685.597 us; speedup vs baseline: 1.1697x; 1.0672x over previous
//
#include <hip/hip_runtime.h>
#include <math.h>

#define BT_TOK 32768
#define D_IN   1024
#define H1D    768
#define H2D    512
#define KCB    512

typedef _Float16 f16;
typedef _Float16 half8v __attribute__((ext_vector_type(8)));
typedef float f32x4 __attribute__((ext_vector_type(4)));

#define GLDS16(g, l) \
    __builtin_amdgcn_global_load_lds((const __attribute__((address_space(1))) void*)(g), \
                                     (__attribute__((address_space(3))) void*)(l), 16, 0, 0)

// split convention: hi = f16(v), lo = f16((v-hi)*2048); v ~= hi + lo/2048
__device__ __forceinline__ void splitf(float v, f16& h, f16& l) {
    h = (f16)v;
    l = (f16)((v - (float)h) * 2048.f);
}

// ---------------------------------------------------------------------------
// Split-FP16 MFMA GEMM — R1-measured-best structure (m97-style):
//   BM=128 x BN=128, BK=64 (two K32 halves), 256 thr = 4 waves (2M x 2N),
//   per-wave 64x64 (4x4 16-tiles), single-buffered 64 KiB LDS ->
//   **2 blocks/CU** (the only config that measured 33.5% MfmaUtil; cross-
//   block wave overlap beats every 1-blk/CU phase schedule tried in R2-R5).
//   Plain __syncthreads() 2-barrier loop; compiler handles waitcnts.
// Pair path (AF32=false): A/B f16 hi/lo, 64-B rows, chunk swizzle
//   slot = s ^ ((row>>1)&3) on BOTH stage-source and frag-read (0-conflict,
//   verified R1/R2).
// AF32 path (GEMM1): A raw fp32, 128-B rows, granule swizzle
//   slot = g ^ (row&7) both sides (verified R4/R5); frags read as 2x
//   ds_read_b128 f32 and split to the f16 pair in-register (saves the
//   384 MB x pre-split pass). Residual ~8-way A-read aliasing ~4% (measured
//   6.3M conflict cycles) - accepted.
// EPI 0: +bias -> f16 pair. 1: VQ tile-argmin. 2: +bias,relu -> f16 pair.
// EPI 3: +bias -> fp32.
// ---------------------------------------------------------------------------
template<int EPI, bool AF32>
__global__ __launch_bounds__(256, 2) void sgemm_k(
    const float* __restrict__ Af,
    const f16* __restrict__ Ah, const f16* __restrict__ Al,
    const f16* __restrict__ Bh, const f16* __restrict__ Bl,
    const float* __restrict__ bias,
    f16* __restrict__ Ch, f16* __restrict__ Cl,
    float* __restrict__ Cf,
    const float* __restrict__ cnorm,
    float* __restrict__ cand_v, int* __restrict__ cand_i,
    int N, int Kd)
{
    // AF32: sAf [0,32K) = [kk:2][128 rows][128 B] | sBh [32K,48K) | sBl [48K,64K)
    // pair: sAh [0,16K) | sAl [16K,32K) | sBh [32K,48K) | sBl [48K,64K)
    //       (B arrays: [kk:2][128 rows][64 B])
    __shared__ __align__(16) char lds[65536];
    char* const ldsb = lds;

    const int t = threadIdx.x;
    const int lane = t & 63, wave = t >> 6;
    const int wm = wave & 1, wn = wave >> 1;

    // XCD-chunked bijective block swizzle (all grids here have nwg % 8 == 0)
    const int nwg = gridDim.x * gridDim.y;
    int flat = blockIdx.y * gridDim.x + blockIdx.x;
    if ((nwg & 7) == 0) flat = (flat & 7) * (nwg >> 3) + (flat >> 3);
    const int bx = flat % gridDim.x;
    const int by = flat / gridDim.x;
    const int row0 = by * 128, col0 = bx * 128;

    f32x4 acc_h[4][4], acc_l[4][4];
#pragma unroll
    for (int i = 0; i < 4; ++i)
#pragma unroll
        for (int j = 0; j < 4; ++j) {
            acc_h[i][j] = (f32x4){0.f, 0.f, 0.f, 0.f};
            acc_l[i][j] = (f32x4){0.f, 0.f, 0.f, 0.f};
        }

    // ---- staging addressing
    // B / A-pair (64-B rows): per GLDS instr 64 rows; row = t>>2, slot = t&3,
    // source chunk = slot ^ ((row>>1)&3) = (t&3)^((t>>3)&3)
    const int srow = t >> 2;
    const int scol = ((t & 3) ^ ((t >> 3) & 3)) * 8;
    const f16* gBh = Bh + (size_t)(col0 + srow) * Kd + scol;
    const f16* gBl = Bl + (size_t)(col0 + srow) * Kd + scol;
    const f16* gAh = AF32 ? nullptr : (Ah + (size_t)(row0 + srow) * Kd + scol);
    const f16* gAl = AF32 ? nullptr : (Al + (size_t)(row0 + srow) * Kd + scol);
    // A fp32 (128-B rows): per instr 32 rows; row = t>>3, granule slot = t&7,
    // source granule = slot ^ (row&7) = (t&7)^((t>>3)&7)
    const float* gAf = AF32 ?
        (Af + (size_t)(row0 + (t >> 3)) * Kd + (((t & 7) ^ ((t >> 3) & 7)) << 2)) : nullptr;

    // ---- fragment read addressing
    const int fr = lane & 15;
    const int c0 = lane >> 4;
    // pair path: read slot = c0 ^ ((row>>1)&3) -> lane-constant ((lane>>1)&3)
    const int fko = ((c0 ^ ((lane >> 1) & 3)) << 4);
    // f32 path: granules {2c0, 2c0+1}, read slot = g ^ (row&7), row&7 == lane&7
    const int offA1 = (((2 * c0) ^ (lane & 7)) << 4);
    const int offA2 = (((2 * c0 + 1) ^ (lane & 7)) << 4);

    for (int k0 = 0; k0 < Kd; k0 += 64) {
#pragma unroll
        for (int kk = 0; kk < 2; ++kk) {
            const size_t kcol = (size_t)(kk * 32 + k0);
            if (AF32) {
#pragma unroll
                for (int j4 = 0; j4 < 4; ++j4)
                    GLDS16(gAf + kcol + (size_t)j4 * 32 * Kd,
                           ldsb + kk * 16384 + j4 * 4096 + t * 16);
            } else {
#pragma unroll
                for (int j2 = 0; j2 < 2; ++j2) {
                    const size_t go = (size_t)j2 * 64 * Kd + kcol;
                    GLDS16(gAh + go, ldsb + kk * 8192 + j2 * 4096 + t * 16);
                    GLDS16(gAl + go, ldsb + 16384 + kk * 8192 + j2 * 4096 + t * 16);
                }
            }
#pragma unroll
            for (int j2 = 0; j2 < 2; ++j2) {
                const size_t go = (size_t)j2 * 64 * Kd + kcol;
                GLDS16(gBh + go, ldsb + 32768 + kk * 8192 + j2 * 4096 + t * 16);
                GLDS16(gBl + go, ldsb + 49152 + kk * 8192 + j2 * 4096 + t * 16);
            }
        }
        __syncthreads();

#pragma unroll
        for (int kk = 0; kk < 2; ++kk) {
            half8v fah[4], fal[4];
            if (AF32) {
#pragma unroll
                for (int mi = 0; mi < 4; ++mi) {
                    const char* pr = ldsb + kk * 16384 + (wm * 64 + mi * 16 + fr) * 128;
                    const f32x4 ra = *(const f32x4*)(pr + offA1);
                    const f32x4 rb = *(const f32x4*)(pr + offA2);
#pragma unroll
                    for (int j = 0; j < 4; ++j) {
                        f16 h, l;
                        splitf(ra[j], h, l); fah[mi][j] = h; fal[mi][j] = l;
                        splitf(rb[j], h, l); fah[mi][j + 4] = h; fal[mi][j + 4] = l;
                    }
                }
            } else {
#pragma unroll
                for (int mi = 0; mi < 4; ++mi) {
                    const int ao = kk * 8192 + (wm * 64 + mi * 16 + fr) * 64 + fko;
                    fah[mi] = *(const half8v*)(ldsb + ao);
                    fal[mi] = *(const half8v*)(ldsb + 16384 + ao);
                }
            }
#pragma unroll
            for (int ni = 0; ni < 4; ++ni) {
                const int bo = 32768 + kk * 8192 + (wn * 64 + ni * 16 + fr) * 64 + fko;
                const half8v fbh = *(const half8v*)(ldsb + bo);
                const half8v fbl = *(const half8v*)(ldsb + 16384 + bo);
#pragma unroll
                for (int mi = 0; mi < 4; ++mi) {
                    acc_h[mi][ni] = __builtin_amdgcn_mfma_f32_16x16x32_f16(
                        fah[mi], fbh, acc_h[mi][ni], 0, 0, 0);
                    acc_l[mi][ni] = __builtin_amdgcn_mfma_f32_16x16x32_f16(
                        fah[mi], fbl, acc_l[mi][ni], 0, 0, 0);
                    acc_l[mi][ni] = __builtin_amdgcn_mfma_f32_16x16x32_f16(
                        fal[mi], fbh, acc_l[mi][ni], 0, 0, 0);
                }
            }
        }
        __syncthreads();
    }

    const int cR = (lane >> 4) * 4;   // C/D: row = quad*4 + reg, col = lane&15
    const int cC = lane & 15;

    if (EPI == 0 || EPI == 2 || EPI == 3) {
#pragma unroll
        for (int ni = 0; ni < 4; ++ni) {
            const int col = col0 + wn * 64 + ni * 16 + cC;
            const float bb = bias[col];
#pragma unroll
            for (int mi = 0; mi < 4; ++mi)
#pragma unroll
                for (int r = 0; r < 4; ++r) {
                    const size_t row = row0 + wm * 64 + mi * 16 + cR + r;
                    float v = acc_h[mi][ni][r] + acc_l[mi][ni][r] * (1.f / 2048.f) + bb;
                    if (EPI == 2) v = fmaxf(v, 0.f);
                    if (EPI == 3) {
                        Cf[row * N + col] = v;
                    } else {
                        f16 vh, vl;
                        splitf(v, vh, vl);
                        Ch[row * N + col] = vh;
                        Cl[row * N + col] = vl;
                    }
                }
        }
    } else {  // EPI == 1: VQ tile argmin
#pragma unroll
        for (int mi = 0; mi < 4; ++mi)
#pragma unroll
            for (int r = 0; r < 4; ++r) {
                float bestv = 1e30f;
                int besti = 0;
#pragma unroll
                for (int ni = 0; ni < 4; ++ni) {
                    const int col = col0 + wn * 64 + ni * 16 + cC;
                    const float v = cnorm[col]
                        - 2.f * (acc_h[mi][ni][r] + acc_l[mi][ni][r] * (1.f / 2048.f));
                    if (v < bestv || (v == bestv && col < besti)) { bestv = v; besti = col; }
                }
#pragma unroll
                for (int m = 1; m < 16; m <<= 1) {
                    const float ov = __shfl_xor(bestv, m);
                    const int oi = __shfl_xor(besti, m);
                    if (ov < bestv || (ov == bestv && oi < besti)) { bestv = ov; besti = oi; }
                }
                if (cC == 0) {
                    const size_t row = row0 + wm * 64 + mi * 16 + cR + r;
                    cand_v[row * 8 + bx * 2 + wn] = bestv;
                    cand_i[row * 8 + bx * 2 + wn] = besti;
                }
            }
    }
}

// ---------------------------------------------------------------------------
// Fused prep: coalesced 32x32 LDS-tile transpose-splits for all 4 weights,
// vectorized codebook split, codebook row norms, sums init.
// ---------------------------------------------------------------------------
__global__ __launch_bounds__(256) void prep_k(
    const float* __restrict__ enc_w1, f16* __restrict__ w1h, f16* __restrict__ w1l,
    const float* __restrict__ enc_w2, f16* __restrict__ w2h, f16* __restrict__ w2l,
    const float* __restrict__ codebook, f16* __restrict__ cbh, f16* __restrict__ cbl,
    const float* __restrict__ dec_w1, f16* __restrict__ dw1h, f16* __restrict__ dw1l,
    const float* __restrict__ dec_w2, f16* __restrict__ dw2h, f16* __restrict__ dw2l,
    float* __restrict__ cnorm, float* __restrict__ sums)
{
    __shared__ float tile[32][33];
    const int b = blockIdx.x;
    const int t = threadIdx.x;
    if (b < 2304) {
        const float* W; f16* Oh; f16* Ol; int K, N, tb;
        if (b < 768)       { W = enc_w1; Oh = w1h;  Ol = w1l;  K = 1024; N = 768;  tb = b; }
        else if (b < 1152) { W = enc_w2; Oh = w2h;  Ol = w2l;  K = 768;  N = 512;  tb = b - 768; }
        else if (b < 1536) { W = dec_w1; Oh = dw1h; Ol = dw1l; K = 512;  N = 768;  tb = b - 1152; }
        else               { W = dec_w2; Oh = dw2h; Ol = dw2l; K = 768;  N = 1024; tb = b - 1536; }
        const int ntx = N >> 5;
        const int tk = tb / ntx, tn = tb - tk * ntx;
        const int k0 = tk << 5, n0 = tn << 5;
        const int tx = t & 31, ty = t >> 5;
#pragma unroll
        for (int p = 0; p < 4; ++p)
            tile[ty + p * 8][tx] = W[(size_t)(k0 + ty + p * 8) * N + n0 + tx];
        __syncthreads();
#pragma unroll
        for (int p = 0; p < 4; ++p) {
            const int row = ty + p * 8;
            f16 h, l; splitf(tile[tx][row], h, l);
            Oh[(size_t)(n0 + row) * K + k0 + tx] = h;
            Ol[(size_t)(n0 + row) * K + k0 + tx] = l;
        }
    } else if (b < 2432) {                // codebook split, vectorized (512x512)
        const size_t i = ((size_t)(b - 2304) * 256 + t) * 8;
        const float4 f0 = *(const float4*)(codebook + i);
        const float4 f1 = *(const float4*)(codebook + i + 4);
        const float fv[8] = {f0.x, f0.y, f0.z, f0.w, f1.x, f1.y, f1.z, f1.w};
        f16 hv[8] __attribute__((aligned(16)));
        f16 lv[8] __attribute__((aligned(16)));
#pragma unroll
        for (int j = 0; j < 8; ++j) splitf(fv[j], hv[j], lv[j]);
        *(half8v*)(cbh + i) = *(half8v*)hv;
        *(half8v*)(cbl + i) = *(half8v*)lv;
    } else if (b < 2560) {                // codebook row sum-squares
        const int lane = t & 63, wid = t >> 6;
        const size_t row = (size_t)(b - 2432) * 4 + wid;
        const float* p = codebook + row * 512;
        float s = 0.f;
#pragma unroll
        for (int e = 0; e < 8; ++e) { const float v = p[lane + e * 64]; s = fmaf(v, v, s); }
#pragma unroll
        for (int m = 1; m < 64; m <<= 1) s += __shfl_xor(s, m);
        if (lane == 0) cnorm[row] = s;
    } else {                              // init loss accumulators
        if (t < 2) sums[t] = 0.f;
    }
}

// ---------------------------------------------------------------------------
// LayerNorm + ReLU on f16 hi/lo pair (in place), fp32 math, vectorized.
// ---------------------------------------------------------------------------
template<int H, bool ENORM>
__global__ __launch_bounds__(256) void ln_pair_k(
    f16* __restrict__ hi, f16* __restrict__ lo, const float* __restrict__ g,
    const float* __restrict__ b, float* __restrict__ enorm)
{
    constexpr int NCH = H / 8;
    constexpr int MAXC = (NCH + 63) / 64;
    const int lane = threadIdx.x & 63;
    const int wid = threadIdx.x >> 6;
    const size_t row = (size_t)blockIdx.x * 4 + wid;
    f16* ph = hi + row * H;
    f16* pl = lo + row * H;

    float h[MAXC * 8];
    float s = 0.f;
#pragma unroll
    for (int e = 0; e < MAXC; ++e) {
        const int c = lane + e * 64;
        if ((NCH % 64 == 0) || c < NCH) {
            const half8v vh = *(const half8v*)(ph + c * 8);
            const half8v vl = *(const half8v*)(pl + c * 8);
#pragma unroll
            for (int j = 0; j < 8; ++j) {
                h[e * 8 + j] = (float)vh[j] + (float)vl[j] * (1.f / 2048.f);
                s += h[e * 8 + j];
            }
        }
    }
#pragma unroll
    for (int m = 1; m < 64; m <<= 1) s += __shfl_xor(s, m);
    const float mu = s * (1.f / H);

    float vs = 0.f;
#pragma unroll
    for (int e = 0; e < MAXC; ++e) {
        const int c = lane + e * 64;
        if ((NCH % 64 == 0) || c < NCH) {
#pragma unroll
            for (int j = 0; j < 8; ++j) {
                const float d = h[e * 8 + j] - mu;
                vs = fmaf(d, d, vs);
            }
        }
    }
#pragma unroll
    for (int m = 1; m < 64; m <<= 1) vs += __shfl_xor(vs, m);
    const float rstd = rsqrtf(vs * (1.f / H) + 1e-5f);

    float q = 0.f;
#pragma unroll
    for (int e = 0; e < MAXC; ++e) {
        const int c = lane + e * 64;
        if ((NCH % 64 == 0) || c < NCH) {
            f16 oh[8] __attribute__((aligned(16)));
            f16 ol[8] __attribute__((aligned(16)));
#pragma unroll
            for (int j = 0; j < 8; ++j) {
                float o = (h[e * 8 + j] - mu) * rstd * g[c * 8 + j] + b[c * 8 + j];
                o = fmaxf(o, 0.f);
                splitf(o, oh[j], ol[j]);
                q = fmaf(o, o, q);
            }
            *(half8v*)(ph + c * 8) = *(half8v*)oh;
            *(half8v*)(pl + c * 8) = *(half8v*)ol;
        }
    }
    if (ENORM) {
#pragma unroll
        for (int m = 1; m < 64; m <<= 1) q += __shfl_xor(q, m);
        if (lane == 0) enorm[row] = q;
    }
}

// ---------------------------------------------------------------------------
// Merged VQ-reduce + recon: 256 blocks x 128 tokens.
// ---------------------------------------------------------------------------
__global__ __launch_bounds__(256) void vqrr_k(
    const float* __restrict__ cand_v, const int* __restrict__ cand_i,
    const float* __restrict__ enorm, float* __restrict__ out_idx_f,
    int* __restrict__ out_idx, float* __restrict__ sums,
    const float* __restrict__ V, const float* __restrict__ x)
{
    __shared__ int sidx[128];
    __shared__ float red[256];
    const int tid = threadIdx.x;
    const int blk = blockIdx.x;

    float commit = 0.f;
    if (tid < 128) {
        const int m = blk * 128 + tid;
        float bv = cand_v[(size_t)m * 8];
        int bi = cand_i[(size_t)m * 8];
#pragma unroll
        for (int tt = 1; tt < 8; ++tt) {
            const float v = cand_v[(size_t)m * 8 + tt];
            const int i = cand_i[(size_t)m * 8 + tt];
            if (v < bv || (v == bv && i < bi)) { bv = v; bi = i; }
        }
        out_idx_f[m] = (float)bi;
        out_idx[m] = bi;
        sidx[tid] = bi;
        commit = enorm[m] + bv;
    }
    red[tid] = (tid < 128) ? commit : 0.f;
    __syncthreads();
    for (int s = 128; s > 0; s >>= 1) {
        if (tid < s) red[tid] += red[tid + s];
        __syncthreads();
    }
    if (tid == 0) atomicAdd(sums + 1, red[0]);
    __syncthreads();

    float ls = 0.f;
    for (int tt = 0; tt < 128; ++tt) {
        const int id = sidx[tt];
        const float4 v4 = ((const float4*)(V + (size_t)id * D_IN))[tid];
        const float4 x4 = ((const float4*)(x + (size_t)(blk * 128 + tt) * D_IN))[tid];
        const float d0 = v4.x - x4.x, d1 = v4.y - x4.y;
        const float d2 = v4.z - x4.z, d3 = v4.w - x4.w;
        ls = fmaf(d0, d0, ls); ls = fmaf(d1, d1, ls);
        ls = fmaf(d2, d2, ls); ls = fmaf(d3, d3, ls);
    }
    __syncthreads();
    red[tid] = ls;
    __syncthreads();
    for (int s = 128; s > 0; s >>= 1) {
        if (tid < s) red[tid] += red[tid + s];
        __syncthreads();
    }
    if (tid == 0) atomicAdd(sums, red[0]);
}

// pooled mean of codebook rows: two-stage for parallelism
__global__ __launch_bounds__(256) void pooled_part_k(
    const int* __restrict__ idx, const float* __restrict__ cb,
    float* __restrict__ part)
{
    const int b = blockIdx.x, c = blockIdx.y;   // grid (64, 8)
    const int d = threadIdx.x;
    float a0 = 0.f, a1 = 0.f;
    for (int t = c * 64; t < c * 64 + 64; ++t) {
        const int id = idx[b * 512 + t];
        a0 += cb[(size_t)id * 512 + d];
        a1 += cb[(size_t)id * 512 + d + 256];
    }
    part[((b * 8 + c) * 512) + d] = a0;
    part[((b * 8 + c) * 512) + d + 256] = a1;
}

// proj (reads ppart directly, folds pooled_fin)
__global__ __launch_bounds__(256) void proj_k(
    const float* __restrict__ part, const float* __restrict__ w1,
    const float* __restrict__ b1, const float* __restrict__ w2,
    const float* __restrict__ b2, float* __restrict__ nproj)
{
    __shared__ float sp[512];
    __shared__ float sh[256];
    __shared__ float red[128];
    const int b = blockIdx.x, tid = threadIdx.x;
    {
        float a0 = 0.f, a1 = 0.f;
#pragma unroll
        for (int c = 0; c < 8; ++c) {
            a0 += part[((b * 8 + c) * 512) + tid];
            a1 += part[((b * 8 + c) * 512) + tid + 256];
        }
        sp[tid] = a0 * (1.f / 512.f);
        sp[tid + 256] = a1 * (1.f / 512.f);
    }
    __syncthreads();

    float acc = b1[tid];
    for (int k = 0; k < 512; ++k) acc = fmaf(sp[k], w1[k * 256 + tid], acc);
    sh[tid] = fmaxf(acc, 0.f);
    __syncthreads();

    float p = 0.f;
    if (tid < 128) {
        p = b2[tid];
        for (int k = 0; k < 256; ++k) p = fmaf(sh[k], w2[k * 128 + tid], p);
        red[tid] = p * p;
    }
    __syncthreads();
    for (int s = 64; s > 0; s >>= 1) {
        if (tid < s) red[tid] += red[tid + s];
        __syncthreads();
    }
    if (tid < 128) {
        const float nrm = fmaxf(sqrtf(red[0]), 1e-12f);
        nproj[b * 128 + tid] = p / nrm;
    }
}

// one block per row i of the 64x64 sim matrix; log-softmax diag term
__global__ __launch_bounds__(256) void sim_k(
    const float* __restrict__ nproj, float* __restrict__ rowterm)
{
    __shared__ float ri[128];
    __shared__ float srow[64];
    const int i = blockIdx.x, t = threadIdx.x;
    if (t < 128) ri[t] = nproj[i * 128 + t];
    __syncthreads();

    const int j = t >> 2, q = t & 3;
    float d = 0.f;
    for (int k = q * 32; k < q * 32 + 32; ++k)
        d = fmaf(ri[k], nproj[j * 128 + k], d);
    d += __shfl_xor(d, 1);
    d += __shfl_xor(d, 2);
    if (q == 0) srow[j] = d * 10.f;   // / TEMP
    __syncthreads();

    if (t < 64) {
        float v = srow[t];
        float mx = v;
#pragma unroll
        for (int m = 1; m < 64; m <<= 1) mx = fmaxf(mx, __shfl_xor(mx, m));
        float e = expf(v - mx);
#pragma unroll
        for (int m = 1; m < 64; m <<= 1) e += __shfl_xor(e, m);
        if (t == 0) rowterm[i] = srow[i] - (mx + logf(e));
    }
}

__global__ __launch_bounds__(64) void final_k(
    const float* __restrict__ rowterm, const float* __restrict__ sums,
    float* __restrict__ out5)
{
    const int t = threadIdx.x;
    float c = rowterm[t];
#pragma unroll
    for (int m = 1; m < 64; m <<= 1) c += __shfl_xor(c, m);
    if (t == 0) {
        const float contr = -c / 64.f;
        const float recon = sums[0] / ((float)BT_TOK * (float)D_IN);
        const float commit = sums[1] / ((float)BT_TOK * (float)H2D);
        const float cbl = commit;
        const float total = recon * 1.0f + commit * 1.0f + cbl * 0.25f + contr * 0.5f;
        out5[0] = total;
        out5[1] = recon;
        out5[2] = commit;
        out5[3] = cbl;
        out5[4] = contr;
    }
}

extern "C" void kernel_launch(void* const* d_in, const int* in_sizes, int n_in,
                              void* d_out, int out_size, void* d_ws, size_t ws_size,
                              hipStream_t stream)
{
    const float* x       = (const float*)d_in[0];
    const float* enc_w1  = (const float*)d_in[1];
    const float* enc_b1  = (const float*)d_in[2];
    const float* ln1_g   = (const float*)d_in[3];
    const float* ln1_b   = (const float*)d_in[4];
    const float* enc_w2  = (const float*)d_in[5];
    const float* enc_b2  = (const float*)d_in[6];
    const float* ln2_g   = (const float*)d_in[7];
    const float* ln2_b   = (const float*)d_in[8];
    const float* codebook= (const float*)d_in[9];
    const float* dec_w1  = (const float*)d_in[10];
    const float* dec_b1  = (const float*)d_in[11];
    const float* dec_w2  = (const float*)d_in[12];
    const float* dec_b2  = (const float*)d_in[13];
    const float* proj_w1 = (const float*)d_in[14];
    const float* proj_b1 = (const float*)d_in[15];
    const float* proj_w2 = (const float*)d_in[16];
    const float* proj_b2 = (const float*)d_in[17];
    float* out = (float*)d_out;

    char* wsb = (char*)d_ws;
    size_t off = 0;
    auto alloc = [&](size_t bytes) {
        void* p = wsb + off;
        off += (bytes + 255) & ~(size_t)255;
        return p;
    };

    f16* h1h  = (f16*)alloc((size_t)BT_TOK * H1D * 2);
    f16* h1l  = (f16*)alloc((size_t)BT_TOK * H1D * 2);
    f16* ench = (f16*)alloc((size_t)BT_TOK * H2D * 2);
    f16* encl = (f16*)alloc((size_t)BT_TOK * H2D * 2);
    f16* w1h  = (f16*)alloc((size_t)H1D * D_IN * 2);
    f16* w1l  = (f16*)alloc((size_t)H1D * D_IN * 2);
    f16* w2h  = (f16*)alloc((size_t)H2D * H1D * 2);
    f16* w2l  = (f16*)alloc((size_t)H2D * H1D * 2);
    f16* cbh  = (f16*)alloc((size_t)KCB * H2D * 2);
    f16* cbl  = (f16*)alloc((size_t)KCB * H2D * 2);
    f16* dw1h = (f16*)alloc((size_t)H1D * H2D * 2);
    f16* dw1l = (f16*)alloc((size_t)H1D * H2D * 2);
    f16* dw2h = (f16*)alloc((size_t)D_IN * H1D * 2);
    f16* dw2l = (f16*)alloc((size_t)D_IN * H1D * 2);
    f16* Uh   = (f16*)alloc((size_t)KCB * H1D * 2);
    f16* Ul   = (f16*)alloc((size_t)KCB * H1D * 2);
    float* Vf = (float*)alloc((size_t)KCB * D_IN * 4);
    float* cnorm  = (float*)alloc(KCB * 4);
    float* enorm  = (float*)alloc(BT_TOK * 4);
    float* cand_v = (float*)alloc((size_t)BT_TOK * 8 * 4);
    int*   cand_i = (int*)alloc((size_t)BT_TOK * 8 * 4);
    int*   idxbuf = (int*)alloc(BT_TOK * 4);
    float* ppart  = (float*)alloc(64 * 8 * 512 * 4);
    float* nproj  = (float*)alloc(64 * 128 * 4);
    float* rowterm= (float*)alloc(64 * 4);
    float* sums   = (float*)alloc(2 * 4);

    const dim3 blk(256);

    prep_k<<<dim3(2561), blk, 0, stream>>>(
        enc_w1, w1h, w1l, enc_w2, w2h, w2l, codebook, cbh, cbl,
        dec_w1, dw1h, dw1l, dec_w2, dw2h, dw2l, cnorm, sums);

    // per-code decoder tables:
    // U = relu(cb @ dec_w1 + b1)  [512 x 768];  V = U @ dec_w2 + b2 [512 x 1024]
    sgemm_k<2, false><<<dim3(H1D / 128, KCB / 128), blk, 0, stream>>>(
        nullptr, cbh, cbl, dw1h, dw1l, dec_b1, Uh, Ul, nullptr,
        nullptr, nullptr, nullptr, H1D, H2D);
    sgemm_k<3, false><<<dim3(D_IN / 128, KCB / 128), blk, 0, stream>>>(
        nullptr, Uh, Ul, dw2h, dw2l, dec_b2, nullptr, nullptr, Vf,
        nullptr, nullptr, nullptr, D_IN, H1D);

    // encoder layer 1: h1 = x @ enc_w1 + b1 (fp32 A staged directly)
    sgemm_k<0, true><<<dim3(H1D / 128, BT_TOK / 128), blk, 0, stream>>>(
        x, nullptr, nullptr, w1h, w1l, enc_b1, h1h, h1l, nullptr,
        nullptr, nullptr, nullptr, H1D, D_IN);
    ln_pair_k<H1D, false><<<dim3(BT_TOK / 4), blk, 0, stream>>>(h1h, h1l, ln1_g, ln1_b, nullptr);

    // encoder layer 2: enc = h1 @ enc_w2 + b2
    sgemm_k<0, false><<<dim3(H2D / 128, BT_TOK / 128), blk, 0, stream>>>(
        nullptr, h1h, h1l, w2h, w2l, enc_b2, ench, encl, nullptr,
        nullptr, nullptr, nullptr, H2D, H1D);
    ln_pair_k<H2D, true><<<dim3(BT_TOK / 4), blk, 0, stream>>>(ench, encl, ln2_g, ln2_b, enorm);

    // VQ scores + tile argmin
    sgemm_k<1, false><<<dim3(KCB / 128, BT_TOK / 128), blk, 0, stream>>>(
        nullptr, ench, encl, cbh, cbl, nullptr, nullptr, nullptr, nullptr,
        cnorm, cand_v, cand_i, KCB, H2D);

    vqrr_k<<<dim3(BT_TOK / 128), blk, 0, stream>>>(
        cand_v, cand_i, enorm, out, idxbuf, sums, Vf, x);

    pooled_part_k<<<dim3(64, 8), blk, 0, stream>>>(idxbuf, codebook, ppart);
    proj_k<<<dim3(64), blk, 0, stream>>>(ppart, proj_w1, proj_b1, proj_w2, proj_b2, nproj);
    sim_k<<<dim3(64), blk, 0, stream>>>(nproj, rowterm);
    final_k<<<dim3(1), dim3(64), 0, stream>>>(rowterm, sums, out + BT_TOK);
}